// Round 5
// baseline (931.107 us; speedup 1.0000x reference)
//
#include <hip/hip_runtime.h>

typedef unsigned short u16;
typedef unsigned int u32;
typedef __attribute__((ext_vector_type(8))) short bf16x8;
typedef __attribute__((ext_vector_type(8))) unsigned short ushort8;
typedef __attribute__((ext_vector_type(4))) float f32x4;
typedef __attribute__((ext_vector_type(4))) unsigned int u32x4;

__device__ __forceinline__ u16 f2bf(float x){
  unsigned u = __builtin_bit_cast(unsigned, x);
  unsigned r = (u + 0x7FFFu + ((u >> 16) & 1u)) >> 16;   // RNE
  return (u16)r;
}
__device__ __forceinline__ float bf2f(u16 h){
  unsigned u = ((unsigned)h) << 16;
  return __builtin_bit_cast(float, u);
}

__device__ __forceinline__ void gld_lds16(const void* g, void* l){
  __builtin_amdgcn_global_load_lds((const __attribute__((address_space(1))) void*)g,
                                   (__attribute__((address_space(3))) void*)l,
                                   16, 0, 0);
}

// ---------------------------------------------------------------------------
// Weight transpose + bf16 hi/lo split, 4 jobs in one dispatch (blockIdx.z).
// W[K][1024] -> WT_hi/WT_lo [1024][Kpad], rows k>=K zero-padded.
// ---------------------------------------------------------------------------
__global__ void wconv_kernel(const float* __restrict__ W0, u16* __restrict__ Th0, u16* __restrict__ Tl0, int K0p,
                             const float* __restrict__ W1, u16* __restrict__ Th1, u16* __restrict__ Tl1, int K1p,
                             const float* __restrict__ W2, u16* __restrict__ Th2, u16* __restrict__ Tl2, int K2p,
                             const float* __restrict__ W3, u16* __restrict__ Th3, u16* __restrict__ Tl3, int K3p)
{
  __shared__ float t[32][33];
  int z = blockIdx.z;
  const float* W = z==0 ? W0 : z==1 ? W1 : z==2 ? W2 : W3;
  u16* Th = z==0 ? Th0 : z==1 ? Th1 : z==2 ? Th2 : Th3;
  u16* Tl = z==0 ? Tl0 : z==1 ? Tl1 : z==2 ? Tl2 : Tl3;
  int Kpad = z==0 ? K0p : z==1 ? K1p : z==2 ? K2p : K3p;
  int K = (Kpad == 768) ? 729 : 1024;
  int k0 = blockIdx.x * 32;
  if (k0 >= Kpad) return;
  int n0 = blockIdx.y * 32;
  int tx = threadIdx.x & 31, ty = threadIdx.x >> 5;
#pragma unroll
  for (int j = 0; j < 4; j++){
    int k = k0 + ty + j*8;
    float v = (k < K) ? W[(size_t)k*1024 + (n0 + tx)] : 0.f;
    t[ty + j*8][tx] = v;
  }
  __syncthreads();
#pragma unroll
  for (int j = 0; j < 4; j++){
    int n = n0 + ty + j*8;
    int k = k0 + tx;
    float v = t[tx][ty + j*8];
    u16 hi = f2bf(v);
    u16 lo = f2bf(v - bf2f(hi));
    size_t idx = (size_t)n*Kpad + k;
    Th[idx] = hi; Tl[idx] = lo;
  }
}

// ---------------------------------------------------------------------------
// feats: 729 bihom section products / kappa -> bf16 hi/lo, padded to 768.
// Vectorized: each lane computes 8 consecutive outputs, ushort8 stores.
// ---------------------------------------------------------------------------
__global__ void feats_kernel(const float* __restrict__ x,
                             u16* __restrict__ fh, u16* __restrict__ fl,
                             int row0)
{
  __shared__ float c[8][28];
  const int tid = threadIdx.x;
  const int lrow0 = blockIdx.x * 8;
  if (tid < 8){
    const float* xr = x + (size_t)(row0 + lrow0 + tid) * 18;
    float kk = 1.f;
#pragma unroll
    for (int f = 0; f < 3; f++){
      float xa = xr[3*f+0], xb = xr[3*f+1], xc = xr[3*f+2];
      float ya = xr[9+3*f+0], yb = xr[9+3*f+1], yc = xr[9+3*f+2];
      int bse = f * 9;
      c[tid][bse+0] = xa*xa + ya*ya;
      c[tid][bse+1] = xa*xb + ya*yb;
      c[tid][bse+2] = xa*xc + ya*yc;
      c[tid][bse+3] = xb*xb + yb*yb;
      c[tid][bse+4] = xb*xc + yb*yc;
      c[tid][bse+5] = xc*xc + yc*yc;
      c[tid][bse+6] = xa*yb - xb*ya;
      c[tid][bse+7] = xa*yc - xc*ya;
      c[tid][bse+8] = xb*yc - xc*yb;
      kk *= (xa*xa+ya*ya + xb*xb+yb*yb + xc*xc+yc*yc);
    }
    c[tid][27] = 1.f / kk;
  }
  __syncthreads();
  // per-row coeff layout: r0:0..5  i0:6..8  r1:9..14  i1:15..17
  //                       r2:18..23 i2:24..26  invk:27
#pragma unroll 1
  for (int jj = 0; jj < 3; jj++){          // 8 rows * 768 = 6144 = 3*256*8
    int base = (jj*256 + tid) * 8;
    int rl = base / 768;                   // 768 % 8 == 0 -> 8 elems same row
    int o0 = base - rl*768;
    const float* cc = c[rl];
    ushort8 vh, vl;
#pragma unroll
    for (int e = 0; e < 8; e++){
      int o = o0 + e;
      float v = 0.f;
      if (o < 729){
        int i12, j; float sgn; bool useR, jr2;
        if (o < 270)      { i12 = o/6;            j = o - i12*6;        sgn =  1.f; useR = true;  jr2 = true;  }
        else if (o < 378) { int t = o-270; i12 = t/3; j = t - i12*3;    sgn = -1.f; useR = false; jr2 = false; }
        else if (o < 513) { int t = o-378; i12 = t/3; j = t - i12*3;    sgn =  1.f; useR = true;  jr2 = false; }
        else              { int t = o-513; i12 = t/6; j = t - i12*6;    sgn = -1.f; useR = false; jr2 = true;  }
        float v12;
        if (useR){
          if (i12 < 36) v12 = cc[i12/6] * cc[9 + i12%6];
          else { int u = i12 - 36; v12 = -(cc[6 + u/3] * cc[15 + u%3]); }
        } else {
          if (i12 < 18) v12 = cc[i12/3] * cc[15 + i12%3];
          else { int u = i12 - 18; v12 = -(cc[6 + u/6] * cc[9 + u%6]); }
        }
        float f2 = jr2 ? cc[18 + j] : cc[24 + j];
        v = sgn * v12 * f2 * cc[27];
      }
      u16 hi = f2bf(v);
      u16 lo = f2bf(v - bf2f(hi));
      vh[e] = hi; vl[e] = lo;
    }
    size_t oi = (size_t)lrow0 * 768 + base;
    *(ushort8*)(fh + oi) = vh;
    *(ushort8*)(fl + oi) = vl;
  }
}

// ---------------------------------------------------------------------------
// Dual-tower GEMM, bf16x2 split precision (3 passes), 256x256 block tile,
// BK=32, 512 threads = 8 waves (2 m-halves x 4 n-quarters), wave tile 128x64.
// 16x16x32 MFMA (verified layout). 2-buffer LDS, counted vmcnt(8) + raw
// second barrier. nb 0..3 -> tower a col-blocks, nb 4..7 -> tower b.
// MODE 0: epilogue (acc+bias)^2 -> bf16 hi/lo, coalesced via LDS pack.
// MODE 1: epilogue (acc+bias)^2 * W3[col], block-col reduce -> partial.
//
// LDS: K-loop: sA[2][2][256][32] u16 (64KB) + sB same (64KB).
// MODE0 epilogue reuses LDS as per-wave u32[64][68] pack tiles (139264 B).
// MODE1 rowsum f32[4][256] at byte 131072.
// ---------------------------------------------------------------------------
#define GEMM_SMEM_BYTES (8*64*68*4)

#define STAGE(BUF) do{ \
    u16* _a = sA + (BUF)*16384; u16* _b = sB + (BUF)*16384; \
    gld_lds16(gAh0, _a + wave*1024);        gld_lds16(gAh1, _a + wave*1024 + 512); \
    gld_lds16(gAl0, _a + 8192 + wave*1024); gld_lds16(gAl1, _a + 8192 + wave*1024 + 512); \
    gld_lds16(gBh0, _b + wave*1024);        gld_lds16(gBh1, _b + wave*1024 + 512); \
    gld_lds16(gBl0, _b + 8192 + wave*1024); gld_lds16(gBl1, _b + 8192 + wave*1024 + 512); \
    gAh0 += 32; gAh1 += 32; gAl0 += 32; gAl1 += 32; \
    gBh0 += 32; gBh1 += 32; gBl0 += 32; gBl1 += 32; \
  }while(0)

#define COMPUTE(BUF) do{ \
    const u16* pA = sA + (BUF)*16384; \
    const u16* pB = sB + (BUF)*16384; \
    bf16x8 bh_[4], bl_[4]; \
    _Pragma("unroll") for (int n_ = 0; n_ < 4; n_++) bh_[n_] = *(const bf16x8*)(pB + (wn*64 + n_*16 + r16)*32 + slot); \
    _Pragma("unroll") for (int n_ = 0; n_ < 4; n_++) bl_[n_] = *(const bf16x8*)(pB + 8192 + (wn*64 + n_*16 + r16)*32 + slot); \
    __builtin_amdgcn_s_setprio(1); \
    _Pragma("unroll") for (int m_ = 0; m_ < 8; m_++){ \
      bf16x8 ah_ = *(const bf16x8*)(pA + (wm*128 + m_*16 + r16)*32 + slot); \
      bf16x8 al_ = *(const bf16x8*)(pA + 8192 + (wm*128 + m_*16 + r16)*32 + slot); \
      _Pragma("unroll") for (int n_ = 0; n_ < 4; n_++) \
        acc[m_][n_] = __builtin_amdgcn_mfma_f32_16x16x32_bf16(ah_, bh_[n_], acc[m_][n_], 0, 0, 0); \
      _Pragma("unroll") for (int n_ = 0; n_ < 4; n_++) \
        acc[m_][n_] = __builtin_amdgcn_mfma_f32_16x16x32_bf16(al_, bh_[n_], acc[m_][n_], 0, 0, 0); \
      _Pragma("unroll") for (int n_ = 0; n_ < 4; n_++) \
        acc[m_][n_] = __builtin_amdgcn_mfma_f32_16x16x32_bf16(ah_, bl_[n_], acc[m_][n_], 0, 0, 0); \
    } \
    __builtin_amdgcn_s_setprio(0); \
  }while(0)

template<int MODE>
__global__ __launch_bounds__(512, 1) void gemm_k(
    const u16* __restrict__ Aha, const u16* __restrict__ Ala,
    const u16* __restrict__ Ahb, const u16* __restrict__ Alb,
    const u16* __restrict__ Bha, const u16* __restrict__ Bla,
    const u16* __restrict__ Bhb, const u16* __restrict__ Blb,
    const float* __restrict__ biasa, const float* __restrict__ biasb,
    u16* __restrict__ Oha, u16* __restrict__ Ola,
    u16* __restrict__ Ohb, u16* __restrict__ Olb,
    const float* __restrict__ W3a_, const float* __restrict__ W3b_,
    float* __restrict__ Pa, float* __restrict__ Pb, int Pstride,
    int K)
{
  extern __shared__ __align__(16) u16 smem[];
  u16* sA = smem;                                  // [2][2][256][32]
  u16* sB = smem + 32768;                          // [2][2][256][32]
  float* rowsum = (float*)(smem + 65536);          // [4][256] (MODE 1)

  // bijective XCD swizzle (nwg = 8*MB, always % 8 == 0); nb fast within XCD
  const int nwg = gridDim.x;
  const int qq = nwg >> 3;
  const int wg = (blockIdx.x & 7) * qq + (blockIdx.x >> 3);
  const int nb = wg & 7;
  const int mb = wg >> 3;
  const int tower = nb >> 2, cnb = nb & 3;

  const u16* Ahi = tower ? Ahb : Aha;
  const u16* Alo = tower ? Alb : Ala;
  const u16* Bhi = tower ? Bhb : Bha;
  const u16* Blo = tower ? Blb : Bla;
  const float* bias = tower ? biasb : biasa;

  const int tid = threadIdx.x;
  const int wave = tid >> 6, lane = tid & 63;
  const int wm = wave >> 2, wn = wave & 3;    // 2 row-halves x 4 col-quarters

  // staging addressing (rule-21 pair: inverse-swizzled global source, linear LDS)
  const int l4 = lane >> 2, ls = lane & 3;
  const int fsw  = (l4 >> 1) & 3;
  const int koff = ((ls ^ fsw) << 3);

  const u16* gAh0 = Ahi + (size_t)(mb*256 + wave*32 + l4) * K + koff;
  const u16* gAh1 = gAh0 + (size_t)16 * K;
  const u16* gAl0 = Alo + (size_t)(mb*256 + wave*32 + l4) * K + koff;
  const u16* gAl1 = gAl0 + (size_t)16 * K;
  const u16* gBh0 = Bhi + (size_t)(cnb*256 + wave*32 + l4) * K + koff;
  const u16* gBh1 = gBh0 + (size_t)16 * K;
  const u16* gBl0 = Blo + (size_t)(cnb*256 + wave*32 + l4) * K + koff;
  const u16* gBl1 = gBl0 + (size_t)16 * K;

  // fragment addressing (swizzled ds_read)
  const int r16 = lane & 15, g = lane >> 4;
  const int fr   = (r16 >> 1) & 3;
  const int slot = ((g ^ fr) << 3);

  f32x4 acc[8][4];
#pragma unroll
  for (int m = 0; m < 8; m++)
#pragma unroll
    for (int n = 0; n < 4; n++)
      acc[m][n] = (f32x4){0.f, 0.f, 0.f, 0.f};

  const int NT = K >> 5;          // 24 or 32
  STAGE(0);

#pragma unroll 1
  for (int t = 0; t < NT; ++t){
    if (t + 1 < NT){
      STAGE((t + 1) & 1);                 // issue next tile's 8 loads early
      asm volatile("s_waitcnt vmcnt(8)\n\ts_barrier" ::: "memory");  // tile t ready
    } else {
      asm volatile("s_waitcnt vmcnt(0)\n\ts_barrier" ::: "memory");
    }
    COMPUTE(t & 1);
    __builtin_amdgcn_s_barrier();   // protect buffer before next STAGE overwrite
  }

  const int gc_base = cnb*256 + wn*64;
  if constexpr (MODE == 0){
    // ---- coalesced epilogue: pack (hi,lo) u32 in per-wave LDS, re-read
    // row-major, 16B global stores (128B contiguous per 8 lanes) ----
    u16* Oh = tower ? Ohb : Oha;
    u16* Ol = tower ? Olb : Ola;
    u32* wreg = (u32*)smem + wave * (64*68);
    float bv[4];
#pragma unroll
    for (int n = 0; n < 4; n++) bv[n] = bias[gc_base + n*16 + r16];
    const int rsub = lane >> 3, csub = (lane & 7) * 8;
#pragma unroll 1
    for (int mh = 0; mh < 2; mh++){
#pragma unroll
      for (int mm = 0; mm < 4; mm++){
#pragma unroll
        for (int n = 0; n < 4; n++){
#pragma unroll
          for (int q = 0; q < 4; q++){
            float val = acc[mh*4 + mm][n][q] + bv[n];
            val = val * val;
            u16 hi = f2bf(val);
            u16 lo = f2bf(val - bf2f(hi));
            int lr = mm*16 + g*4 + q, lc = n*16 + r16;
            wreg[lr*68 + lc] = ((u32)hi << 16) | lo;
          }
        }
      }
      asm volatile("s_waitcnt lgkmcnt(0)" ::: "memory");  // writes -> reads (RAW)
#pragma unroll
      for (int rr = 0; rr < 8; rr++){
        int lr = rr*8 + rsub;
        u32x4 a0 = *(const u32x4*)(wreg + lr*68 + csub);
        u32x4 a1 = *(const u32x4*)(wreg + lr*68 + csub + 4);
        ushort8 vh, vl;
#pragma unroll
        for (int i = 0; i < 4; i++){
          vh[i]   = (u16)(a0[i] >> 16); vl[i]   = (u16)(a0[i] & 0xFFFFu);
          vh[4+i] = (u16)(a1[i] >> 16); vl[4+i] = (u16)(a1[i] & 0xFFFFu);
        }
        size_t go = (size_t)(mb*256 + wm*128 + mh*64 + lr) * 1024 + gc_base + csub;
        *(ushort8*)(Oh + go) = vh;
        *(ushort8*)(Ol + go) = vl;
      }
      asm volatile("s_waitcnt lgkmcnt(0)" ::: "memory");  // reads -> next writes (WAR)
    }
  } else {
    const float* W3 = tower ? W3b_ : W3a_;
    float w3v[4], bv[4];
#pragma unroll
    for (int n = 0; n < 4; n++){
      int col = gc_base + n*16 + r16;
      w3v[n] = W3[col];
      bv[n]  = bias[col];
    }
    float rp[8][4];
#pragma unroll
    for (int m = 0; m < 8; m++)
#pragma unroll
      for (int q = 0; q < 4; q++)
        rp[m][q] = 0.f;
#pragma unroll
    for (int m = 0; m < 8; m++)
#pragma unroll
      for (int n = 0; n < 4; n++)
#pragma unroll
        for (int q = 0; q < 4; q++){
          float v = acc[m][n][q] + bv[n];
          rp[m][q] += v * v * w3v[n];
        }
#pragma unroll
    for (int m = 0; m < 8; m++)
#pragma unroll
      for (int q = 0; q < 4; q++){
        float s = rp[m][q];
        s += __shfl_xor(s, 1); s += __shfl_xor(s, 2);
        s += __shfl_xor(s, 4); s += __shfl_xor(s, 8);
        rp[m][q] = s;
      }
    if (r16 == 0){
#pragma unroll
      for (int m = 0; m < 8; m++)
#pragma unroll
        for (int q = 0; q < 4; q++)
          rowsum[wn*256 + wm*128 + m*16 + g*4 + q] = rp[m][q];
    }
    __syncthreads();
    if (tid < 256){
      float s = rowsum[tid] + rowsum[256 + tid] + rowsum[512 + tid] + rowsum[768 + tid];
      float* P = tower ? Pb : Pa;
      P[(size_t)cnb * Pstride + mb*256 + tid] = s;
    }
  }
}

// ---------------------------------------------------------------------------
// finalize: a3 = b3 + sum_j partial[j][row]; out = clip(2log|a3a|*Wfa - ..b..)
// ---------------------------------------------------------------------------
__global__ void finalize_kernel(const float* __restrict__ Pa, const float* __restrict__ Pb,
                                int Pstride,
                                const float* __restrict__ b3a, const float* __restrict__ Wfa,
                                const float* __restrict__ b3b, const float* __restrict__ Wfb,
                                float* __restrict__ out, int row0, int Rc)
{
  int r = blockIdx.x * 256 + threadIdx.x;
  if (r >= Rc) return;
  float sa = b3a[0], sb = b3b[0];
#pragma unroll
  for (int j = 0; j < 4; j++){
    sa += Pa[(size_t)j * Pstride + r];
    sb += Pb[(size_t)j * Pstride + r];
  }
  float ta = 2.f * logf(fabsf(sa)) * Wfa[0];
  float tb = 2.f * logf(fabsf(sb)) * Wfb[0];
  float o = ta - tb;
  o = fminf(fmaxf(o, -1000000.f), 1000000.f);
  out[row0 + r] = o;
}

// ---------------------------------------------------------------------------
static inline size_t align256(size_t v){ return (v + 255) & ~(size_t)255; }

extern "C" void kernel_launch(void* const* d_in, const int* in_sizes, int n_in,
                              void* d_out, int out_size, void* d_ws, size_t ws_size,
                              hipStream_t stream)
{
  (void)n_in; (void)out_size;
  const float* x   = (const float*)d_in[0];
  const float* W1a = (const float*)d_in[1];
  const float* b1a = (const float*)d_in[2];
  const float* W2a = (const float*)d_in[3];
  const float* b2a = (const float*)d_in[4];
  const float* W3a = (const float*)d_in[5];
  const float* b3a = (const float*)d_in[6];
  const float* Wfa = (const float*)d_in[7];
  const float* W1b = (const float*)d_in[8];
  const float* b1b = (const float*)d_in[9];
  const float* W2b = (const float*)d_in[10];
  const float* b2b = (const float*)d_in[11];
  const float* W3b = (const float*)d_in[12];
  const float* b3b = (const float*)d_in[13];
  const float* Wfb = (const float*)d_in[14];
  float* out = (float*)d_out;

  const int B  = in_sizes[0] / 18;
  const int K1 = 768;
  const int K2 = 1024;

  hipFuncSetAttribute((const void*)gemm_k<0>,
                      hipFuncAttributeMaxDynamicSharedMemorySize, GEMM_SMEM_BYTES);
  hipFuncSetAttribute((const void*)gemm_k<1>,
                      hipFuncAttributeMaxDynamicSharedMemorySize, GEMM_SMEM_BYTES);

  char* base = (char*)d_ws;
  size_t off = 0;
  auto carve = [&](size_t bytes) -> char* {
    off = align256(off);
    char* p = base + off;
    off += bytes;
    return p;
  };

  u16* wt1ah = (u16*)carve((size_t)1024 * K1 * 2);
  u16* wt1al = (u16*)carve((size_t)1024 * K1 * 2);
  u16* wt2ah = (u16*)carve((size_t)1024 * K2 * 2);
  u16* wt2al = (u16*)carve((size_t)1024 * K2 * 2);
  u16* wt1bh = (u16*)carve((size_t)1024 * K1 * 2);
  u16* wt1bl = (u16*)carve((size_t)1024 * K1 * 2);
  u16* wt2bh = (u16*)carve((size_t)1024 * K2 * 2);
  u16* wt2bl = (u16*)carve((size_t)1024 * K2 * 2);

  size_t fixed = align256(off);
  const long long per_row = (long long)K1*4 + 8192 + 32;
  long long avail = (long long)ws_size - (long long)fixed - 8192;
  long long rmax = avail > 0 ? avail / per_row : 0;
  int R = (int)((rmax / 256) * 256);
  if (R > B) R = B;
  if (R < 256) R = 256;

  u16* fh   = (u16*)carve((size_t)R * K1 * 2);
  u16* fl   = (u16*)carve((size_t)R * K1 * 2);
  u16* h1ah = (u16*)carve((size_t)R * 1024 * 2);
  u16* h1al = (u16*)carve((size_t)R * 1024 * 2);
  u16* h1bh = (u16*)carve((size_t)R * 1024 * 2);
  u16* h1bl = (u16*)carve((size_t)R * 1024 * 2);
  float* pa = (float*)carve((size_t)4 * R * 4);
  float* pb = (float*)carve((size_t)4 * R * 4);

  // all four weight transposes in one dispatch
  wconv_kernel<<<dim3(32, 32, 4), 256, 0, stream>>>(
      W1a, wt1ah, wt1al, K1,
      W2a, wt2ah, wt2al, K2,
      W1b, wt1bh, wt1bl, K1,
      W2b, wt2bh, wt2bl, K2);

  for (int row0 = 0; row0 < B; row0 += R){
    int Rc = B - row0; if (Rc > R) Rc = R;
    int MB = Rc / 256;
    feats_kernel<<<Rc/8, 256, 0, stream>>>(x, fh, fl, row0);
    gemm_k<0><<<dim3(8*MB), 512, GEMM_SMEM_BYTES, stream>>>(
        fh, fl, fh, fl,
        wt1ah, wt1al, wt1bh, wt1bl,
        b1a, b1b,
        h1ah, h1al, h1bh, h1bl,
        nullptr, nullptr, nullptr, nullptr, 0, K1);
    gemm_k<1><<<dim3(8*MB), 512, GEMM_SMEM_BYTES, stream>>>(
        h1ah, h1al, h1bh, h1bl,
        wt2ah, wt2al, wt2bh, wt2bl,
        b2a, b2b,
        nullptr, nullptr, nullptr, nullptr,
        W3a, W3b, pa, pb, R, K2);
    finalize_kernel<<<(Rc + 255)/256, 256, 0, stream>>>(pa, pb, R, b3a, Wfa, b3b, Wfb,
                                                        out, row0, Rc);
  }
}

// Round 6
// 811.654 us; speedup vs baseline: 1.1472x; 1.1472x over previous
//
#include <hip/hip_runtime.h>

typedef unsigned short u16;
typedef unsigned int u32;
typedef __attribute__((ext_vector_type(8))) short bf16x8;
typedef __attribute__((ext_vector_type(4))) float f32x4;

__device__ __forceinline__ u16 f2bf(float x){
  unsigned u = __builtin_bit_cast(unsigned, x);
  unsigned r = (u + 0x7FFFu + ((u >> 16) & 1u)) >> 16;   // RNE
  return (u16)r;
}
__device__ __forceinline__ float bf2f(u16 h){
  unsigned u = ((unsigned)h) << 16;
  return __builtin_bit_cast(float, u);
}

__device__ __forceinline__ void gld_lds16(const void* g, void* l){
  __builtin_amdgcn_global_load_lds((const __attribute__((address_space(1))) void*)g,
                                   (__attribute__((address_space(3))) void*)l,
                                   16, 0, 0);
}

// ---------------------------------------------------------------------------
// Weight transpose + bf16 hi/lo split, 4 jobs in one dispatch (blockIdx.z).
// W[K][1024] -> WT_hi/WT_lo [1024][Kpad], rows k>=K zero-padded.
// ---------------------------------------------------------------------------
__global__ void wconv_kernel(const float* __restrict__ W0, u16* __restrict__ Th0, u16* __restrict__ Tl0, int K0p,
                             const float* __restrict__ W1, u16* __restrict__ Th1, u16* __restrict__ Tl1, int K1p,
                             const float* __restrict__ W2, u16* __restrict__ Th2, u16* __restrict__ Tl2, int K2p,
                             const float* __restrict__ W3, u16* __restrict__ Th3, u16* __restrict__ Tl3, int K3p)
{
  __shared__ float t[32][33];
  int z = blockIdx.z;
  const float* W = z==0 ? W0 : z==1 ? W1 : z==2 ? W2 : W3;
  u16* Th = z==0 ? Th0 : z==1 ? Th1 : z==2 ? Th2 : Th3;
  u16* Tl = z==0 ? Tl0 : z==1 ? Tl1 : z==2 ? Tl2 : Tl3;
  int Kpad = z==0 ? K0p : z==1 ? K1p : z==2 ? K2p : K3p;
  int K = (Kpad == 768) ? 729 : 1024;
  int k0 = blockIdx.x * 32;
  if (k0 >= Kpad) return;
  int n0 = blockIdx.y * 32;
  int tx = threadIdx.x & 31, ty = threadIdx.x >> 5;
#pragma unroll
  for (int j = 0; j < 4; j++){
    int k = k0 + ty + j*8;
    float v = (k < K) ? W[(size_t)k*1024 + (n0 + tx)] : 0.f;
    t[ty + j*8][tx] = v;
  }
  __syncthreads();
#pragma unroll
  for (int j = 0; j < 4; j++){
    int n = n0 + ty + j*8;
    int k = k0 + tx;
    float v = t[tx][ty + j*8];
    u16 hi = f2bf(v);
    u16 lo = f2bf(v - bf2f(hi));
    size_t idx = (size_t)n*Kpad + k;
    Th[idx] = hi; Tl[idx] = lo;
  }
}

// ---------------------------------------------------------------------------
// feats, LUT-restructured: per block (8 rows), build per-row product tables
// tA[8][81] (r45 entries 0..44, i36 entries 45..80; internal signs folded)
// and tB[8][9] (r2 0..5, i2 6..8) in LDS ONCE; each thread resolves its 3
// column descriptors (idxA, idxB, region sign) ONCE and applies them to all
// 8 rows. Removes the per-(row,element) divide/branch tree (~60 -> ~8 ops).
// ---------------------------------------------------------------------------
__global__ void feats_kernel(const float* __restrict__ x,
                             u16* __restrict__ fh, u16* __restrict__ fl,
                             int row0)
{
  __shared__ float cC[8][28];
  __shared__ float tA[8][81];
  __shared__ float tB[8][12];
  __shared__ float ivk[8];
  const int tid = threadIdx.x;
  const int lrow0 = blockIdx.x * 8;
  if (tid < 8){
    const float* xr = x + (size_t)(row0 + lrow0 + tid) * 18;
    float kk = 1.f;
#pragma unroll
    for (int f = 0; f < 3; f++){
      float xa = xr[3*f+0], xb = xr[3*f+1], xc = xr[3*f+2];
      float ya = xr[9+3*f+0], yb = xr[9+3*f+1], yc = xr[9+3*f+2];
      int bse = f * 9;
      cC[tid][bse+0] = xa*xa + ya*ya;
      cC[tid][bse+1] = xa*xb + ya*yb;
      cC[tid][bse+2] = xa*xc + ya*yc;
      cC[tid][bse+3] = xb*xb + yb*yb;
      cC[tid][bse+4] = xb*xc + yb*yc;
      cC[tid][bse+5] = xc*xc + yc*yc;
      cC[tid][bse+6] = xa*yb - xb*ya;
      cC[tid][bse+7] = xa*yc - xc*ya;
      cC[tid][bse+8] = xb*yc - xc*yb;
      kk *= (xa*xa+ya*ya + xb*xb+yb*yb + xc*xc+yc*yc);
    }
    ivk[tid] = 1.f / kk;
#pragma unroll
    for (int j = 0; j < 6; j++) tB[tid][j] = cC[tid][18+j];
#pragma unroll
    for (int j = 0; j < 3; j++) tB[tid][6+j] = cC[tid][24+j];
  }
  __syncthreads();
  // build tA: 8 rows x 81 entries = 648
#pragma unroll 1
  for (int e = tid; e < 648; e += 256){
    int r = e / 81;
    int k = e - r*81;
    const float* cc = cC[r];
    float val;
    if (k < 36)      {               val =   cc[k/6]     * cc[9  + k%6]; }
    else if (k < 45) { int u = k-36; val = -(cc[6 + u/3] * cc[15 + u%3]); }
    else if (k < 63) { int u = k-45; val =   cc[u/3]     * cc[15 + u%3]; }
    else             { int u = k-63; val = -(cc[6 + u/6] * cc[9  + u%6]); }
    tA[r][k] = val;
  }
  __syncthreads();
  // 3 columns per thread; descriptor once, applied to 8 rows
#pragma unroll 1
  for (int jj = 0; jj < 3; jj++){
    int o = jj*256 + tid;
    int idxA = 0, idxB = 0; float sgn = 0.f;
    if (o < 270)      {              idxA = o/6;      idxB = o - (o/6)*6; sgn =  1.f; }
    else if (o < 378) { int t = o-270; idxA = 45 + t/3; idxB = 6 + t%3;   sgn = -1.f; }
    else if (o < 513) { int t = o-378; idxA = t/3;      idxB = 6 + t%3;   sgn =  1.f; }
    else if (o < 729) { int t = o-513; idxA = 45 + t/6; idxB = t%6;       sgn = -1.f; }
#pragma unroll
    for (int r = 0; r < 8; r++){
      float v = sgn * tA[r][idxA] * tB[r][idxB] * ivk[r];
      u16 hi = f2bf(v);
      u16 lo = f2bf(v - bf2f(hi));
      size_t oi = (size_t)(lrow0 + r) * 768 + o;
      fh[oi] = hi; fl[oi] = lo;
    }
  }
}

// ---------------------------------------------------------------------------
// Dual-tower GEMM, bf16x2 split precision (3 passes), 256x256 block tile,
// BK=32, 512 threads = 8 waves (2 m-halves x 4 n-quarters), wave tile 128x64.
// 16x16x32 MFMA (verified layout). 2-buffer LDS, counted vmcnt(8) + raw
// second barrier. nb 0..3 -> tower a col-blocks, nb 4..7 -> tower b.
// MODE 0: epilogue (acc+bias)^2 -> bf16 hi/lo (R4 scalar-store form, proven).
// MODE 1: epilogue (acc+bias)^2 * W3[col], block-col reduce -> partial.
// ---------------------------------------------------------------------------
#define GEMM_SMEM_BYTES (2*65536 + 4*256*4)

#define STAGE(BUF) do{ \
    u16* _a = sA + (BUF)*16384; u16* _b = sB + (BUF)*16384; \
    gld_lds16(gAh0, _a + wave*1024);        gld_lds16(gAh1, _a + wave*1024 + 512); \
    gld_lds16(gAl0, _a + 8192 + wave*1024); gld_lds16(gAl1, _a + 8192 + wave*1024 + 512); \
    gld_lds16(gBh0, _b + wave*1024);        gld_lds16(gBh1, _b + wave*1024 + 512); \
    gld_lds16(gBl0, _b + 8192 + wave*1024); gld_lds16(gBl1, _b + 8192 + wave*1024 + 512); \
    gAh0 += 32; gAh1 += 32; gAl0 += 32; gAl1 += 32; \
    gBh0 += 32; gBh1 += 32; gBl0 += 32; gBl1 += 32; \
  }while(0)

#define COMPUTE(BUF) do{ \
    const u16* pA = sA + (BUF)*16384; \
    const u16* pB = sB + (BUF)*16384; \
    bf16x8 bh_[4], bl_[4]; \
    _Pragma("unroll") for (int n_ = 0; n_ < 4; n_++) bh_[n_] = *(const bf16x8*)(pB + (wn*64 + n_*16 + r16)*32 + slot); \
    _Pragma("unroll") for (int n_ = 0; n_ < 4; n_++) bl_[n_] = *(const bf16x8*)(pB + 8192 + (wn*64 + n_*16 + r16)*32 + slot); \
    __builtin_amdgcn_s_setprio(1); \
    _Pragma("unroll") for (int m_ = 0; m_ < 8; m_++){ \
      bf16x8 ah_ = *(const bf16x8*)(pA + (wm*128 + m_*16 + r16)*32 + slot); \
      bf16x8 al_ = *(const bf16x8*)(pA + 8192 + (wm*128 + m_*16 + r16)*32 + slot); \
      _Pragma("unroll") for (int n_ = 0; n_ < 4; n_++) \
        acc[m_][n_] = __builtin_amdgcn_mfma_f32_16x16x32_bf16(ah_, bh_[n_], acc[m_][n_], 0, 0, 0); \
      _Pragma("unroll") for (int n_ = 0; n_ < 4; n_++) \
        acc[m_][n_] = __builtin_amdgcn_mfma_f32_16x16x32_bf16(al_, bh_[n_], acc[m_][n_], 0, 0, 0); \
      _Pragma("unroll") for (int n_ = 0; n_ < 4; n_++) \
        acc[m_][n_] = __builtin_amdgcn_mfma_f32_16x16x32_bf16(ah_, bl_[n_], acc[m_][n_], 0, 0, 0); \
    } \
    __builtin_amdgcn_s_setprio(0); \
  }while(0)

template<int MODE>
__global__ __launch_bounds__(512, 1) void gemm_k(
    const u16* __restrict__ Aha, const u16* __restrict__ Ala,
    const u16* __restrict__ Ahb, const u16* __restrict__ Alb,
    const u16* __restrict__ Bha, const u16* __restrict__ Bla,
    const u16* __restrict__ Bhb, const u16* __restrict__ Blb,
    const float* __restrict__ biasa, const float* __restrict__ biasb,
    u16* __restrict__ Oha, u16* __restrict__ Ola,
    u16* __restrict__ Ohb, u16* __restrict__ Olb,
    const float* __restrict__ W3a_, const float* __restrict__ W3b_,
    float* __restrict__ Pa, float* __restrict__ Pb, int Pstride,
    int K)
{
  extern __shared__ __align__(16) u16 smem[];
  u16* sA = smem;                                  // [2][2][256][32]
  u16* sB = smem + 32768;                          // [2][2][256][32]
  float* rowsum = (float*)(smem + 65536);          // [4][256] (MODE 1)

  // bijective XCD swizzle (nwg = 8*MB, always % 8 == 0); nb fast within XCD
  const int nwg = gridDim.x;
  const int qq = nwg >> 3;
  const int wg = (blockIdx.x & 7) * qq + (blockIdx.x >> 3);
  const int nb = wg & 7;
  const int mb = wg >> 3;
  const int tower = nb >> 2, cnb = nb & 3;

  const u16* Ahi = tower ? Ahb : Aha;
  const u16* Alo = tower ? Alb : Ala;
  const u16* Bhi = tower ? Bhb : Bha;
  const u16* Blo = tower ? Blb : Bla;
  const float* bias = tower ? biasb : biasa;

  const int tid = threadIdx.x;
  const int wave = tid >> 6, lane = tid & 63;
  const int wm = wave >> 2, wn = wave & 3;    // 2 row-halves x 4 col-quarters

  // staging addressing (rule-21 pair: inverse-swizzled global source, linear LDS)
  const int l4 = lane >> 2, ls = lane & 3;
  const int fsw  = (l4 >> 1) & 3;
  const int koff = ((ls ^ fsw) << 3);

  const u16* gAh0 = Ahi + (size_t)(mb*256 + wave*32 + l4) * K + koff;
  const u16* gAh1 = gAh0 + (size_t)16 * K;
  const u16* gAl0 = Alo + (size_t)(mb*256 + wave*32 + l4) * K + koff;
  const u16* gAl1 = gAl0 + (size_t)16 * K;
  const u16* gBh0 = Bhi + (size_t)(cnb*256 + wave*32 + l4) * K + koff;
  const u16* gBh1 = gBh0 + (size_t)16 * K;
  const u16* gBl0 = Blo + (size_t)(cnb*256 + wave*32 + l4) * K + koff;
  const u16* gBl1 = gBl0 + (size_t)16 * K;

  // fragment addressing (swizzled ds_read)
  const int r16 = lane & 15, g = lane >> 4;
  const int fr   = (r16 >> 1) & 3;
  const int slot = ((g ^ fr) << 3);

  f32x4 acc[8][4];
#pragma unroll
  for (int m = 0; m < 8; m++)
#pragma unroll
    for (int n = 0; n < 4; n++)
      acc[m][n] = (f32x4){0.f, 0.f, 0.f, 0.f};

  const int NT = K >> 5;          // 24 or 32
  STAGE(0);

#pragma unroll 1
  for (int t = 0; t < NT; ++t){
    if (t + 1 < NT){
      STAGE((t + 1) & 1);                 // issue next tile's 8 loads early
      asm volatile("s_waitcnt vmcnt(8)\n\ts_barrier" ::: "memory");  // tile t ready
    } else {
      asm volatile("s_waitcnt vmcnt(0)\n\ts_barrier" ::: "memory");
    }
    COMPUTE(t & 1);
    __builtin_amdgcn_s_barrier();   // protect buffer before next STAGE overwrite
  }

  if constexpr (MODE == 0){
    u16* Oh = tower ? Ohb : Oha;
    u16* Ol = tower ? Olb : Ola;
#pragma unroll
    for (int n = 0; n < 4; n++){
      int col = cnb*256 + wn*64 + n*16 + r16;
      float bv = bias[col];
#pragma unroll
      for (int m = 0; m < 8; m++){
        int rbase = mb*256 + wm*128 + m*16 + g*4;
#pragma unroll
        for (int q = 0; q < 4; q++){
          float val = acc[m][n][q] + bv;
          val = val * val;
          u16 hi = f2bf(val);
          u16 lo = f2bf(val - bf2f(hi));
          size_t oi = (size_t)(rbase + q) * 1024 + col;
          Oh[oi] = hi; Ol[oi] = lo;
        }
      }
    }
  } else {
    const float* W3 = tower ? W3b_ : W3a_;
    float w3v[4], bv[4];
#pragma unroll
    for (int n = 0; n < 4; n++){
      int col = cnb*256 + wn*64 + n*16 + r16;
      w3v[n] = W3[col];
      bv[n]  = bias[col];
    }
    float rp[8][4];
#pragma unroll
    for (int m = 0; m < 8; m++)
#pragma unroll
      for (int q = 0; q < 4; q++)
        rp[m][q] = 0.f;
#pragma unroll
    for (int m = 0; m < 8; m++)
#pragma unroll
      for (int n = 0; n < 4; n++)
#pragma unroll
        for (int q = 0; q < 4; q++){
          float v = acc[m][n][q] + bv[n];
          rp[m][q] += v * v * w3v[n];
        }
#pragma unroll
    for (int m = 0; m < 8; m++)
#pragma unroll
      for (int q = 0; q < 4; q++){
        float s = rp[m][q];
        s += __shfl_xor(s, 1); s += __shfl_xor(s, 2);
        s += __shfl_xor(s, 4); s += __shfl_xor(s, 8);
        rp[m][q] = s;
      }
    if (r16 == 0){
#pragma unroll
      for (int m = 0; m < 8; m++)
#pragma unroll
        for (int q = 0; q < 4; q++)
          rowsum[wn*256 + wm*128 + m*16 + g*4 + q] = rp[m][q];
    }
    __syncthreads();
    if (tid < 256){
      float s = rowsum[tid] + rowsum[256 + tid] + rowsum[512 + tid] + rowsum[768 + tid];
      float* P = tower ? Pb : Pa;
      P[(size_t)cnb * Pstride + mb*256 + tid] = s;
    }
  }
}

// ---------------------------------------------------------------------------
// finalize: a3 = b3 + sum_j partial[j][row]; out = clip(2log|a3a|*Wfa - ..b..)
// ---------------------------------------------------------------------------
__global__ void finalize_kernel(const float* __restrict__ Pa, const float* __restrict__ Pb,
                                int Pstride,
                                const float* __restrict__ b3a, const float* __restrict__ Wfa,
                                const float* __restrict__ b3b, const float* __restrict__ Wfb,
                                float* __restrict__ out, int row0, int Rc)
{
  int r = blockIdx.x * 256 + threadIdx.x;
  if (r >= Rc) return;
  float sa = b3a[0], sb = b3b[0];
#pragma unroll
  for (int j = 0; j < 4; j++){
    sa += Pa[(size_t)j * Pstride + r];
    sb += Pb[(size_t)j * Pstride + r];
  }
  float ta = 2.f * logf(fabsf(sa)) * Wfa[0];
  float tb = 2.f * logf(fabsf(sb)) * Wfb[0];
  float o = ta - tb;
  o = fminf(fmaxf(o, -1000000.f), 1000000.f);
  out[row0 + r] = o;
}

// ---------------------------------------------------------------------------
static inline size_t align256(size_t v){ return (v + 255) & ~(size_t)255; }

extern "C" void kernel_launch(void* const* d_in, const int* in_sizes, int n_in,
                              void* d_out, int out_size, void* d_ws, size_t ws_size,
                              hipStream_t stream)
{
  (void)n_in; (void)out_size;
  const float* x   = (const float*)d_in[0];
  const float* W1a = (const float*)d_in[1];
  const float* b1a = (const float*)d_in[2];
  const float* W2a = (const float*)d_in[3];
  const float* b2a = (const float*)d_in[4];
  const float* W3a = (const float*)d_in[5];
  const float* b3a = (const float*)d_in[6];
  const float* Wfa = (const float*)d_in[7];
  const float* W1b = (const float*)d_in[8];
  const float* b1b = (const float*)d_in[9];
  const float* W2b = (const float*)d_in[10];
  const float* b2b = (const float*)d_in[11];
  const float* W3b = (const float*)d_in[12];
  const float* b3b = (const float*)d_in[13];
  const float* Wfb = (const float*)d_in[14];
  float* out = (float*)d_out;

  const int B  = in_sizes[0] / 18;
  const int K1 = 768;
  const int K2 = 1024;

  hipFuncSetAttribute((const void*)gemm_k<0>,
                      hipFuncAttributeMaxDynamicSharedMemorySize, GEMM_SMEM_BYTES);
  hipFuncSetAttribute((const void*)gemm_k<1>,
                      hipFuncAttributeMaxDynamicSharedMemorySize, GEMM_SMEM_BYTES);

  char* base = (char*)d_ws;
  size_t off = 0;
  auto carve = [&](size_t bytes) -> char* {
    off = align256(off);
    char* p = base + off;
    off += bytes;
    return p;
  };

  u16* wt1ah = (u16*)carve((size_t)1024 * K1 * 2);
  u16* wt1al = (u16*)carve((size_t)1024 * K1 * 2);
  u16* wt2ah = (u16*)carve((size_t)1024 * K2 * 2);
  u16* wt2al = (u16*)carve((size_t)1024 * K2 * 2);
  u16* wt1bh = (u16*)carve((size_t)1024 * K1 * 2);
  u16* wt1bl = (u16*)carve((size_t)1024 * K1 * 2);
  u16* wt2bh = (u16*)carve((size_t)1024 * K2 * 2);
  u16* wt2bl = (u16*)carve((size_t)1024 * K2 * 2);

  size_t fixed = align256(off);
  const long long per_row = (long long)K1*4 + 8192 + 32;
  long long avail = (long long)ws_size - (long long)fixed - 8192;
  long long rmax = avail > 0 ? avail / per_row : 0;
  int R = (int)((rmax / 256) * 256);
  if (R > B) R = B;
  if (R < 256) R = 256;

  u16* fh   = (u16*)carve((size_t)R * K1 * 2);
  u16* fl   = (u16*)carve((size_t)R * K1 * 2);
  u16* h1ah = (u16*)carve((size_t)R * 1024 * 2);
  u16* h1al = (u16*)carve((size_t)R * 1024 * 2);
  u16* h1bh = (u16*)carve((size_t)R * 1024 * 2);
  u16* h1bl = (u16*)carve((size_t)R * 1024 * 2);
  float* pa = (float*)carve((size_t)4 * R * 4);
  float* pb = (float*)carve((size_t)4 * R * 4);

  // all four weight transposes in one dispatch
  wconv_kernel<<<dim3(32, 32, 4), 256, 0, stream>>>(
      W1a, wt1ah, wt1al, K1,
      W2a, wt2ah, wt2al, K2,
      W1b, wt1bh, wt1bl, K1,
      W2b, wt2bh, wt2bl, K2);

  for (int row0 = 0; row0 < B; row0 += R){
    int Rc = B - row0; if (Rc > R) Rc = R;
    int MB = Rc / 256;
    feats_kernel<<<Rc/8, 256, 0, stream>>>(x, fh, fl, row0);
    gemm_k<0><<<dim3(8*MB), 512, GEMM_SMEM_BYTES, stream>>>(
        fh, fl, fh, fl,
        wt1ah, wt1al, wt1bh, wt1bl,
        b1a, b1b,
        h1ah, h1al, h1bh, h1bl,
        nullptr, nullptr, nullptr, nullptr, 0, K1);
    gemm_k<1><<<dim3(8*MB), 512, GEMM_SMEM_BYTES, stream>>>(
        h1ah, h1al, h1bh, h1bl,
        wt2ah, wt2al, wt2bh, wt2bl,
        b2a, b2b,
        nullptr, nullptr, nullptr, nullptr,
        W3a, W3b, pa, pb, R, K2);
    finalize_kernel<<<(Rc + 255)/256, 256, 0, stream>>>(pa, pb, R, b3a, Wfa, b3b, Wfb,
                                                        out, row0, Rc);
  }
}

// Round 7
// 695.220 us; speedup vs baseline: 1.3393x; 1.1675x over previous
//
#include <hip/hip_runtime.h>

typedef unsigned short u16;
typedef unsigned int u32;
typedef __attribute__((ext_vector_type(8))) short bf16x8;
typedef __attribute__((ext_vector_type(4))) float f32x4;

__device__ __forceinline__ u16 f2bf(float x){
  unsigned u = __builtin_bit_cast(unsigned, x);
  unsigned r = (u + 0x7FFFu + ((u >> 16) & 1u)) >> 16;   // RNE
  return (u16)r;
}
__device__ __forceinline__ float bf2f(u16 h){
  unsigned u = ((unsigned)h) << 16;
  return __builtin_bit_cast(float, u);
}

__device__ __forceinline__ void gld_lds16(const void* g, void* l){
  __builtin_amdgcn_global_load_lds((const __attribute__((address_space(1))) void*)g,
                                   (__attribute__((address_space(3))) void*)l,
                                   16, 0, 0);
}

// ---------------------------------------------------------------------------
// Weight transpose + bf16 hi/lo split, 4 jobs in one dispatch (blockIdx.z).
// W[K][1024] -> WT_hi/WT_lo [1024][Kpad], rows k>=K zero-padded.
// ---------------------------------------------------------------------------
__global__ void wconv_kernel(const float* __restrict__ W0, u16* __restrict__ Th0, u16* __restrict__ Tl0, int K0p,
                             const float* __restrict__ W1, u16* __restrict__ Th1, u16* __restrict__ Tl1, int K1p,
                             const float* __restrict__ W2, u16* __restrict__ Th2, u16* __restrict__ Tl2, int K2p,
                             const float* __restrict__ W3, u16* __restrict__ Th3, u16* __restrict__ Tl3, int K3p)
{
  __shared__ float t[32][33];
  int z = blockIdx.z;
  const float* W = z==0 ? W0 : z==1 ? W1 : z==2 ? W2 : W3;
  u16* Th = z==0 ? Th0 : z==1 ? Th1 : z==2 ? Th2 : Th3;
  u16* Tl = z==0 ? Tl0 : z==1 ? Tl1 : z==2 ? Tl2 : Tl3;
  int Kpad = z==0 ? K0p : z==1 ? K1p : z==2 ? K2p : K3p;
  int K = (Kpad == 768) ? 729 : 1024;
  int k0 = blockIdx.x * 32;
  if (k0 >= Kpad) return;
  int n0 = blockIdx.y * 32;
  int tx = threadIdx.x & 31, ty = threadIdx.x >> 5;
#pragma unroll
  for (int j = 0; j < 4; j++){
    int k = k0 + ty + j*8;
    float v = (k < K) ? W[(size_t)k*1024 + (n0 + tx)] : 0.f;
    t[ty + j*8][tx] = v;
  }
  __syncthreads();
#pragma unroll
  for (int j = 0; j < 4; j++){
    int n = n0 + ty + j*8;
    int k = k0 + tx;
    float v = t[tx][ty + j*8];
    u16 hi = f2bf(v);
    u16 lo = f2bf(v - bf2f(hi));
    size_t idx = (size_t)n*Kpad + k;
    Th[idx] = hi; Tl[idx] = lo;
  }
}

// ---------------------------------------------------------------------------
// feats, LUT-restructured (R6 form, proven): per block (8 rows), build
// per-row product tables tA[8][81], tB[8][12], ivk[8] once; each thread
// resolves its 3 column descriptors once and applies them to all 8 rows.
// ---------------------------------------------------------------------------
__global__ void feats_kernel(const float* __restrict__ x,
                             u16* __restrict__ fh, u16* __restrict__ fl,
                             int row0)
{
  __shared__ float cC[8][28];
  __shared__ float tA[8][81];
  __shared__ float tB[8][12];
  __shared__ float ivk[8];
  const int tid = threadIdx.x;
  const int lrow0 = blockIdx.x * 8;
  if (tid < 8){
    const float* xr = x + (size_t)(row0 + lrow0 + tid) * 18;
    float kk = 1.f;
#pragma unroll
    for (int f = 0; f < 3; f++){
      float xa = xr[3*f+0], xb = xr[3*f+1], xc = xr[3*f+2];
      float ya = xr[9+3*f+0], yb = xr[9+3*f+1], yc = xr[9+3*f+2];
      int bse = f * 9;
      cC[tid][bse+0] = xa*xa + ya*ya;
      cC[tid][bse+1] = xa*xb + ya*yb;
      cC[tid][bse+2] = xa*xc + ya*yc;
      cC[tid][bse+3] = xb*xb + yb*yb;
      cC[tid][bse+4] = xb*xc + yb*yc;
      cC[tid][bse+5] = xc*xc + yc*yc;
      cC[tid][bse+6] = xa*yb - xb*ya;
      cC[tid][bse+7] = xa*yc - xc*ya;
      cC[tid][bse+8] = xb*yc - xc*yb;
      kk *= (xa*xa+ya*ya + xb*xb+yb*yb + xc*xc+yc*yc);
    }
    ivk[tid] = 1.f / kk;
#pragma unroll
    for (int j = 0; j < 6; j++) tB[tid][j] = cC[tid][18+j];
#pragma unroll
    for (int j = 0; j < 3; j++) tB[tid][6+j] = cC[tid][24+j];
  }
  __syncthreads();
#pragma unroll 1
  for (int e = tid; e < 648; e += 256){
    int r = e / 81;
    int k = e - r*81;
    const float* cc = cC[r];
    float val;
    if (k < 36)      {               val =   cc[k/6]     * cc[9  + k%6]; }
    else if (k < 45) { int u = k-36; val = -(cc[6 + u/3] * cc[15 + u%3]); }
    else if (k < 63) { int u = k-45; val =   cc[u/3]     * cc[15 + u%3]; }
    else             { int u = k-63; val = -(cc[6 + u/6] * cc[9  + u%6]); }
    tA[r][k] = val;
  }
  __syncthreads();
#pragma unroll 1
  for (int jj = 0; jj < 3; jj++){
    int o = jj*256 + tid;
    int idxA = 0, idxB = 0; float sgn = 0.f;
    if (o < 270)      {              idxA = o/6;      idxB = o - (o/6)*6; sgn =  1.f; }
    else if (o < 378) { int t = o-270; idxA = 45 + t/3; idxB = 6 + t%3;   sgn = -1.f; }
    else if (o < 513) { int t = o-378; idxA = t/3;      idxB = 6 + t%3;   sgn =  1.f; }
    else if (o < 729) { int t = o-513; idxA = 45 + t/6; idxB = t%6;       sgn = -1.f; }
#pragma unroll
    for (int r = 0; r < 8; r++){
      float v = sgn * tA[r][idxA] * tB[r][idxB] * ivk[r];
      u16 hi = f2bf(v);
      u16 lo = f2bf(v - bf2f(hi));
      size_t oi = (size_t)(lrow0 + r) * 768 + o;
      fh[oi] = hi; fl[oi] = lo;
    }
  }
}

// ---------------------------------------------------------------------------
// Single-tower GEMM, bf16x2 split precision (3 passes), 256x256 block tile,
// BK=32, 512 threads = 8 waves (2 m-halves x 4 n-quarters), wave tile 128x64.
// 16x16x32 MFMA (verified layout). 2-buffer LDS, counted vmcnt(8) + raw
// second barrier. nb 0..3 col-blocks (N=1024). Grid = 4*MB = 512 blocks
// at full B -> exactly 2 blocks/CU, no tail.
// MODE 0: epilogue (acc+bias)^2 -> bf16 hi/lo (layer 1)
// MODE 1: epilogue (acc+bias)^2 * W3[col], block-col reduce -> partial (layer 2)
// ---------------------------------------------------------------------------
#define GEMM_SMEM_BYTES (2*65536 + 4*256*4)

#define STAGE(BUF) do{ \
    u16* _a = sA + (BUF)*16384; u16* _b = sB + (BUF)*16384; \
    gld_lds16(gAh0, _a + wave*1024);        gld_lds16(gAh1, _a + wave*1024 + 512); \
    gld_lds16(gAl0, _a + 8192 + wave*1024); gld_lds16(gAl1, _a + 8192 + wave*1024 + 512); \
    gld_lds16(gBh0, _b + wave*1024);        gld_lds16(gBh1, _b + wave*1024 + 512); \
    gld_lds16(gBl0, _b + 8192 + wave*1024); gld_lds16(gBl1, _b + 8192 + wave*1024 + 512); \
    gAh0 += 32; gAh1 += 32; gAl0 += 32; gAl1 += 32; \
    gBh0 += 32; gBh1 += 32; gBl0 += 32; gBl1 += 32; \
  }while(0)

#define COMPUTE(BUF) do{ \
    const u16* pA = sA + (BUF)*16384; \
    const u16* pB = sB + (BUF)*16384; \
    bf16x8 bh_[4], bl_[4]; \
    _Pragma("unroll") for (int n_ = 0; n_ < 4; n_++) bh_[n_] = *(const bf16x8*)(pB + (wn*64 + n_*16 + r16)*32 + slot); \
    _Pragma("unroll") for (int n_ = 0; n_ < 4; n_++) bl_[n_] = *(const bf16x8*)(pB + 8192 + (wn*64 + n_*16 + r16)*32 + slot); \
    __builtin_amdgcn_s_setprio(1); \
    _Pragma("unroll") for (int m_ = 0; m_ < 8; m_++){ \
      bf16x8 ah_ = *(const bf16x8*)(pA + (wm*128 + m_*16 + r16)*32 + slot); \
      bf16x8 al_ = *(const bf16x8*)(pA + 8192 + (wm*128 + m_*16 + r16)*32 + slot); \
      _Pragma("unroll") for (int n_ = 0; n_ < 4; n_++) \
        acc[m_][n_] = __builtin_amdgcn_mfma_f32_16x16x32_bf16(ah_, bh_[n_], acc[m_][n_], 0, 0, 0); \
      _Pragma("unroll") for (int n_ = 0; n_ < 4; n_++) \
        acc[m_][n_] = __builtin_amdgcn_mfma_f32_16x16x32_bf16(al_, bh_[n_], acc[m_][n_], 0, 0, 0); \
      _Pragma("unroll") for (int n_ = 0; n_ < 4; n_++) \
        acc[m_][n_] = __builtin_amdgcn_mfma_f32_16x16x32_bf16(ah_, bl_[n_], acc[m_][n_], 0, 0, 0); \
    } \
    __builtin_amdgcn_s_setprio(0); \
  }while(0)

template<int MODE>
__global__ __launch_bounds__(512, 1) void gemm_k(
    const u16* __restrict__ Ahi, const u16* __restrict__ Alo,
    const u16* __restrict__ Bhi, const u16* __restrict__ Blo,
    const float* __restrict__ bias,
    u16* __restrict__ Oh, u16* __restrict__ Ol,
    const float* __restrict__ W3, float* __restrict__ P, int Pstride,
    int K)
{
  extern __shared__ __align__(16) u16 smem[];
  u16* sA = smem;                                  // [2][2][256][32]
  u16* sB = smem + 32768;                          // [2][2][256][32]
  float* rowsum = (float*)(smem + 65536);          // [4][256] (MODE 1)

  // bijective XCD swizzle (nwg = 4*MB, always % 8 == 0 at MB>=2)
  const int nwg = gridDim.x;
  const int qq = nwg >> 3;
  const int wg = (blockIdx.x & 7) * qq + (blockIdx.x >> 3);
  const int nb = wg & 3;
  const int mb = wg >> 2;

  const int tid = threadIdx.x;
  const int wave = tid >> 6, lane = tid & 63;
  const int wm = wave >> 2, wn = wave & 3;    // 2 row-halves x 4 col-quarters

  // staging addressing (rule-21 pair: inverse-swizzled global source, linear LDS)
  const int l4 = lane >> 2, ls = lane & 3;
  const int fsw  = (l4 >> 1) & 3;
  const int koff = ((ls ^ fsw) << 3);

  const u16* gAh0 = Ahi + (size_t)(mb*256 + wave*32 + l4) * K + koff;
  const u16* gAh1 = gAh0 + (size_t)16 * K;
  const u16* gAl0 = Alo + (size_t)(mb*256 + wave*32 + l4) * K + koff;
  const u16* gAl1 = gAl0 + (size_t)16 * K;
  const u16* gBh0 = Bhi + (size_t)(nb*256 + wave*32 + l4) * K + koff;
  const u16* gBh1 = gBh0 + (size_t)16 * K;
  const u16* gBl0 = Blo + (size_t)(nb*256 + wave*32 + l4) * K + koff;
  const u16* gBl1 = gBl0 + (size_t)16 * K;

  // fragment addressing (swizzled ds_read)
  const int r16 = lane & 15, g = lane >> 4;
  const int fr   = (r16 >> 1) & 3;
  const int slot = ((g ^ fr) << 3);

  f32x4 acc[8][4];
#pragma unroll
  for (int m = 0; m < 8; m++)
#pragma unroll
    for (int n = 0; n < 4; n++)
      acc[m][n] = (f32x4){0.f, 0.f, 0.f, 0.f};

  const int NT = K >> 5;          // 24 or 32
  STAGE(0);

#pragma unroll 1
  for (int t = 0; t < NT; ++t){
    if (t + 1 < NT){
      STAGE((t + 1) & 1);                 // issue next tile's 8 loads early
      asm volatile("s_waitcnt vmcnt(8)\n\ts_barrier" ::: "memory");  // tile t ready
    } else {
      asm volatile("s_waitcnt vmcnt(0)\n\ts_barrier" ::: "memory");
    }
    COMPUTE(t & 1);
    __builtin_amdgcn_s_barrier();   // protect buffer before next STAGE overwrite
  }

  if constexpr (MODE == 0){
#pragma unroll
    for (int n = 0; n < 4; n++){
      int col = nb*256 + wn*64 + n*16 + r16;
      float bv = bias[col];
#pragma unroll
      for (int m = 0; m < 8; m++){
        int rbase = mb*256 + wm*128 + m*16 + g*4;
#pragma unroll
        for (int q = 0; q < 4; q++){
          float val = acc[m][n][q] + bv;
          val = val * val;
          u16 hi = f2bf(val);
          u16 lo = f2bf(val - bf2f(hi));
          size_t oi = (size_t)(rbase + q) * 1024 + col;
          Oh[oi] = hi; Ol[oi] = lo;
        }
      }
    }
  } else {
    float w3v[4], bv[4];
#pragma unroll
    for (int n = 0; n < 4; n++){
      int col = nb*256 + wn*64 + n*16 + r16;
      w3v[n] = W3[col];
      bv[n]  = bias[col];
    }
    float rp[8][4];
#pragma unroll
    for (int m = 0; m < 8; m++)
#pragma unroll
      for (int q = 0; q < 4; q++)
        rp[m][q] = 0.f;
#pragma unroll
    for (int m = 0; m < 8; m++)
#pragma unroll
      for (int n = 0; n < 4; n++)
#pragma unroll
        for (int q = 0; q < 4; q++){
          float v = acc[m][n][q] + bv[n];
          rp[m][q] += v * v * w3v[n];
        }
#pragma unroll
    for (int m = 0; m < 8; m++)
#pragma unroll
      for (int q = 0; q < 4; q++){
        float s = rp[m][q];
        s += __shfl_xor(s, 1); s += __shfl_xor(s, 2);
        s += __shfl_xor(s, 4); s += __shfl_xor(s, 8);
        rp[m][q] = s;
      }
    if (r16 == 0){
#pragma unroll
      for (int m = 0; m < 8; m++)
#pragma unroll
        for (int q = 0; q < 4; q++)
          rowsum[wn*256 + wm*128 + m*16 + g*4 + q] = rp[m][q];
    }
    __syncthreads();
    if (tid < 256){
      float s = rowsum[tid] + rowsum[256 + tid] + rowsum[512 + tid] + rowsum[768 + tid];
      P[(size_t)nb * Pstride + mb*256 + tid] = s;
    }
  }
}

// ---------------------------------------------------------------------------
// finalize: a3 = b3 + sum_j partial[j][row]; out = clip(2log|a3a|*Wfa - ..b..)
// ---------------------------------------------------------------------------
__global__ void finalize_kernel(const float* __restrict__ Pa, const float* __restrict__ Pb,
                                int Pstride,
                                const float* __restrict__ b3a, const float* __restrict__ Wfa,
                                const float* __restrict__ b3b, const float* __restrict__ Wfb,
                                float* __restrict__ out, int row0, int Rc)
{
  int r = blockIdx.x * 256 + threadIdx.x;
  if (r >= Rc) return;
  float sa = b3a[0], sb = b3b[0];
#pragma unroll
  for (int j = 0; j < 4; j++){
    sa += Pa[(size_t)j * Pstride + r];
    sb += Pb[(size_t)j * Pstride + r];
  }
  float ta = 2.f * logf(fabsf(sa)) * Wfa[0];
  float tb = 2.f * logf(fabsf(sb)) * Wfb[0];
  float o = ta - tb;
  o = fminf(fmaxf(o, -1000000.f), 1000000.f);
  out[row0 + r] = o;
}

// ---------------------------------------------------------------------------
static inline size_t align256(size_t v){ return (v + 255) & ~(size_t)255; }

extern "C" void kernel_launch(void* const* d_in, const int* in_sizes, int n_in,
                              void* d_out, int out_size, void* d_ws, size_t ws_size,
                              hipStream_t stream)
{
  (void)n_in; (void)out_size;
  const float* x   = (const float*)d_in[0];
  const float* W1a = (const float*)d_in[1];
  const float* b1a = (const float*)d_in[2];
  const float* W2a = (const float*)d_in[3];
  const float* b2a = (const float*)d_in[4];
  const float* W3a = (const float*)d_in[5];
  const float* b3a = (const float*)d_in[6];
  const float* Wfa = (const float*)d_in[7];
  const float* W1b = (const float*)d_in[8];
  const float* b1b = (const float*)d_in[9];
  const float* W2b = (const float*)d_in[10];
  const float* b2b = (const float*)d_in[11];
  const float* W3b = (const float*)d_in[12];
  const float* b3b = (const float*)d_in[13];
  const float* Wfb = (const float*)d_in[14];
  float* out = (float*)d_out;

  const int B  = in_sizes[0] / 18;
  const int K1 = 768;
  const int K2 = 1024;

  hipFuncSetAttribute((const void*)gemm_k<0>,
                      hipFuncAttributeMaxDynamicSharedMemorySize, GEMM_SMEM_BYTES);
  hipFuncSetAttribute((const void*)gemm_k<1>,
                      hipFuncAttributeMaxDynamicSharedMemorySize, GEMM_SMEM_BYTES);

  char* base = (char*)d_ws;
  size_t off = 0;
  auto carve = [&](size_t bytes) -> char* {
    off = align256(off);
    char* p = base + off;
    off += bytes;
    return p;
  };

  u16* wt1ah = (u16*)carve((size_t)1024 * K1 * 2);
  u16* wt1al = (u16*)carve((size_t)1024 * K1 * 2);
  u16* wt2ah = (u16*)carve((size_t)1024 * K2 * 2);
  u16* wt2al = (u16*)carve((size_t)1024 * K2 * 2);
  u16* wt1bh = (u16*)carve((size_t)1024 * K1 * 2);
  u16* wt1bl = (u16*)carve((size_t)1024 * K1 * 2);
  u16* wt2bh = (u16*)carve((size_t)1024 * K2 * 2);
  u16* wt2bl = (u16*)carve((size_t)1024 * K2 * 2);

  size_t fixed = align256(off);
  // per-row live set: feats hi+lo (3072) + ONE tower's h1 hi+lo (4096) + partials (32)
  const long long per_row = (long long)K1*4 + 4096 + 32;
  long long avail = (long long)ws_size - (long long)fixed - 8192;
  long long rmax = avail > 0 ? avail / per_row : 0;
  int R = (int)((rmax / 256) * 256);
  if (R > B) R = B;
  if (R < 256) R = 256;

  u16* fh   = (u16*)carve((size_t)R * K1 * 2);
  u16* fl   = (u16*)carve((size_t)R * K1 * 2);
  u16* h1h  = (u16*)carve((size_t)R * 1024 * 2);   // reused by both towers
  u16* h1l  = (u16*)carve((size_t)R * 1024 * 2);
  float* pa = (float*)carve((size_t)4 * R * 4);
  float* pb = (float*)carve((size_t)4 * R * 4);

  // all four weight transposes in one dispatch
  wconv_kernel<<<dim3(32, 32, 4), 256, 0, stream>>>(
      W1a, wt1ah, wt1al, K1,
      W2a, wt2ah, wt2al, K2,
      W1b, wt1bh, wt1bl, K1,
      W2b, wt2bh, wt2bl, K2);

  for (int row0 = 0; row0 < B; row0 += R){
    int Rc = B - row0; if (Rc > R) Rc = R;
    int MB = Rc / 256;
    feats_kernel<<<Rc/8, 256, 0, stream>>>(x, fh, fl, row0);
    // tower a
    gemm_k<0><<<dim3(4*MB), 512, GEMM_SMEM_BYTES, stream>>>(
        fh, fl, wt1ah, wt1al, b1a, h1h, h1l, nullptr, nullptr, 0, K1);
    gemm_k<1><<<dim3(4*MB), 512, GEMM_SMEM_BYTES, stream>>>(
        h1h, h1l, wt2ah, wt2al, b2a, nullptr, nullptr, W3a, pa, R, K2);
    // tower b (reuses h1 buffers)
    gemm_k<0><<<dim3(4*MB), 512, GEMM_SMEM_BYTES, stream>>>(
        fh, fl, wt1bh, wt1bl, b1b, h1h, h1l, nullptr, nullptr, 0, K1);
    gemm_k<1><<<dim3(4*MB), 512, GEMM_SMEM_BYTES, stream>>>(
        h1h, h1l, wt2bh, wt2bl, b2b, nullptr, nullptr, W3b, pb, R, K2);
    finalize_kernel<<<(Rc + 255)/256, 256, 0, stream>>>(pa, pb, R, b3a, Wfa, b3b, Wfb,
                                                        out, row0, Rc);
  }
}

// Round 8
// 675.608 us; speedup vs baseline: 1.3782x; 1.0290x over previous
//
#include <hip/hip_runtime.h>

typedef unsigned short u16;
typedef unsigned int u32;
typedef __attribute__((ext_vector_type(8))) short bf16x8;
typedef __attribute__((ext_vector_type(4))) float f32x4;

__device__ __forceinline__ u16 f2bf(float x){
  unsigned u = __builtin_bit_cast(unsigned, x);
  unsigned r = (u + 0x7FFFu + ((u >> 16) & 1u)) >> 16;   // RNE
  return (u16)r;
}
__device__ __forceinline__ float bf2f(u16 h){
  unsigned u = ((unsigned)h) << 16;
  return __builtin_bit_cast(float, u);
}

__device__ __forceinline__ void gld_lds16(const void* g, void* l){
  __builtin_amdgcn_global_load_lds((const __attribute__((address_space(1))) void*)g,
                                   (__attribute__((address_space(3))) void*)l,
                                   16, 0, 0);
}

// ---------------------------------------------------------------------------
// Weight transpose + bf16 hi/lo split, 4 jobs in one dispatch (blockIdx.z).
// ---------------------------------------------------------------------------
__global__ void wconv_kernel(const float* __restrict__ W0, u16* __restrict__ Th0, u16* __restrict__ Tl0, int K0p,
                             const float* __restrict__ W1, u16* __restrict__ Th1, u16* __restrict__ Tl1, int K1p,
                             const float* __restrict__ W2, u16* __restrict__ Th2, u16* __restrict__ Tl2, int K2p,
                             const float* __restrict__ W3, u16* __restrict__ Th3, u16* __restrict__ Tl3, int K3p)
{
  __shared__ float t[32][33];
  int z = blockIdx.z;
  const float* W = z==0 ? W0 : z==1 ? W1 : z==2 ? W2 : W3;
  u16* Th = z==0 ? Th0 : z==1 ? Th1 : z==2 ? Th2 : Th3;
  u16* Tl = z==0 ? Tl0 : z==1 ? Tl1 : z==2 ? Tl2 : Tl3;
  int Kpad = z==0 ? K0p : z==1 ? K1p : z==2 ? K2p : K3p;
  int K = (Kpad == 768) ? 729 : 1024;
  int k0 = blockIdx.x * 32;
  if (k0 >= Kpad) return;
  int n0 = blockIdx.y * 32;
  int tx = threadIdx.x & 31, ty = threadIdx.x >> 5;
#pragma unroll
  for (int j = 0; j < 4; j++){
    int k = k0 + ty + j*8;
    float v = (k < K) ? W[(size_t)k*1024 + (n0 + tx)] : 0.f;
    t[ty + j*8][tx] = v;
  }
  __syncthreads();
#pragma unroll
  for (int j = 0; j < 4; j++){
    int n = n0 + ty + j*8;
    int k = k0 + tx;
    float v = t[tx][ty + j*8];
    u16 hi = f2bf(v);
    u16 lo = f2bf(v - bf2f(hi));
    size_t idx = (size_t)n*Kpad + k;
    Th[idx] = hi; Tl[idx] = lo;
  }
}

// ---------------------------------------------------------------------------
// feats, LUT-restructured (R6 form, proven).
// ---------------------------------------------------------------------------
__global__ void feats_kernel(const float* __restrict__ x,
                             u16* __restrict__ fh, u16* __restrict__ fl,
                             int row0)
{
  __shared__ float cC[8][28];
  __shared__ float tA[8][81];
  __shared__ float tB[8][12];
  __shared__ float ivk[8];
  const int tid = threadIdx.x;
  const int lrow0 = blockIdx.x * 8;
  if (tid < 8){
    const float* xr = x + (size_t)(row0 + lrow0 + tid) * 18;
    float kk = 1.f;
#pragma unroll
    for (int f = 0; f < 3; f++){
      float xa = xr[3*f+0], xb = xr[3*f+1], xc = xr[3*f+2];
      float ya = xr[9+3*f+0], yb = xr[9+3*f+1], yc = xr[9+3*f+2];
      int bse = f * 9;
      cC[tid][bse+0] = xa*xa + ya*ya;
      cC[tid][bse+1] = xa*xb + ya*yb;
      cC[tid][bse+2] = xa*xc + ya*yc;
      cC[tid][bse+3] = xb*xb + yb*yb;
      cC[tid][bse+4] = xb*xc + yb*yc;
      cC[tid][bse+5] = xc*xc + yc*yc;
      cC[tid][bse+6] = xa*yb - xb*ya;
      cC[tid][bse+7] = xa*yc - xc*ya;
      cC[tid][bse+8] = xb*yc - xc*yb;
      kk *= (xa*xa+ya*ya + xb*xb+yb*yb + xc*xc+yc*yc);
    }
    ivk[tid] = 1.f / kk;
#pragma unroll
    for (int j = 0; j < 6; j++) tB[tid][j] = cC[tid][18+j];
#pragma unroll
    for (int j = 0; j < 3; j++) tB[tid][6+j] = cC[tid][24+j];
  }
  __syncthreads();
#pragma unroll 1
  for (int e = tid; e < 648; e += 256){
    int r = e / 81;
    int k = e - r*81;
    const float* cc = cC[r];
    float val;
    if (k < 36)      {               val =   cc[k/6]     * cc[9  + k%6]; }
    else if (k < 45) { int u = k-36; val = -(cc[6 + u/3] * cc[15 + u%3]); }
    else if (k < 63) { int u = k-45; val =   cc[u/3]     * cc[15 + u%3]; }
    else             { int u = k-63; val = -(cc[6 + u/6] * cc[9  + u%6]); }
    tA[r][k] = val;
  }
  __syncthreads();
#pragma unroll 1
  for (int jj = 0; jj < 3; jj++){
    int o = jj*256 + tid;
    int idxA = 0, idxB = 0; float sgn = 0.f;
    if (o < 270)      {              idxA = o/6;      idxB = o - (o/6)*6; sgn =  1.f; }
    else if (o < 378) { int t = o-270; idxA = 45 + t/3; idxB = 6 + t%3;   sgn = -1.f; }
    else if (o < 513) { int t = o-378; idxA = t/3;      idxB = 6 + t%3;   sgn =  1.f; }
    else if (o < 729) { int t = o-513; idxA = 45 + t/6; idxB = t%6;       sgn = -1.f; }
#pragma unroll
    for (int r = 0; r < 8; r++){
      float v = sgn * tA[r][idxA] * tB[r][idxB] * ivk[r];
      u16 hi = f2bf(v);
      u16 lo = f2bf(v - bf2f(hi));
      size_t oi = (size_t)(lrow0 + r) * 768 + o;
      fh[oi] = hi; fl[oi] = lo;
    }
  }
}

// ---------------------------------------------------------------------------
// Single-tower GEMM, bf16x2 split precision (3 passes), 256x256 block tile,
// BK=32, 512 threads = 8 waves (2 m-halves x 4 n-quarters), wave tile 128x64.
// K-loop: m201-style 6-phase schedule. Each phase:
//   {ds_read frags ; prefetch gloads ; s_barrier ; lgkmcnt(0) ;
//    setprio(1) ; 16 MFMA ; setprio(0) ; s_barrier}
// P1: bh+ah0-3 | pf A    P2: ah4-7 | pf B    P3: al0-3    P4: al4-7
// P5: bl                P6: (regs only) ; closing vmcnt(0)+barrier.
// Next tile's 8 loads issued P1/P2 -> ~4 phases of latency slack.
// ---------------------------------------------------------------------------
#define GEMM_SMEM_BYTES (2*65536 + 4*256*4)

#define STAGE_A1(BUF) do{ u16* _a = sA + (BUF)*16384; \
    gld_lds16(gAh0, _a + wave*1024); gld_lds16(gAh1, _a + wave*1024 + 512); \
    gAh0 += 32; gAh1 += 32; }while(0)
#define STAGE_A2(BUF) do{ u16* _a = sA + (BUF)*16384; \
    gld_lds16(gAl0, _a + 8192 + wave*1024); gld_lds16(gAl1, _a + 8192 + wave*1024 + 512); \
    gAl0 += 32; gAl1 += 32; }while(0)
#define STAGE_B1(BUF) do{ u16* _b = sB + (BUF)*16384; \
    gld_lds16(gBh0, _b + wave*1024); gld_lds16(gBh1, _b + wave*1024 + 512); \
    gBh0 += 32; gBh1 += 32; }while(0)
#define STAGE_B2(BUF) do{ u16* _b = sB + (BUF)*16384; \
    gld_lds16(gBl0, _b + 8192 + wave*1024); gld_lds16(gBl1, _b + 8192 + wave*1024 + 512); \
    gBl0 += 32; gBl1 += 32; }while(0)

#define BARRIER()  asm volatile("s_barrier" ::: "memory")
#define LGKM0()    asm volatile("s_waitcnt lgkmcnt(0)" ::: "memory")

// 16-MFMA cluster: acc[O..O+3][0..3] += A[0..3] x B[0..3]
#define CLUSTER(A, O, B) do{ \
    __builtin_amdgcn_s_setprio(1); \
    _Pragma("unroll") for (int m_ = 0; m_ < 4; m_++) \
      _Pragma("unroll") for (int n_ = 0; n_ < 4; n_++) \
        acc[(O)+m_][n_] = __builtin_amdgcn_mfma_f32_16x16x32_bf16((A)[m_], (B)[n_], acc[(O)+m_][n_], 0, 0, 0); \
    __builtin_amdgcn_s_setprio(0); \
  }while(0)

template<int MODE>
__global__ __launch_bounds__(512, 1) void gemm_k(
    const u16* __restrict__ Ahi, const u16* __restrict__ Alo,
    const u16* __restrict__ Bhi, const u16* __restrict__ Blo,
    const float* __restrict__ bias,
    u16* __restrict__ Oh, u16* __restrict__ Ol,
    const float* __restrict__ W3, float* __restrict__ P, int Pstride,
    int K)
{
  extern __shared__ __align__(16) u16 smem[];
  u16* sA = smem;                                  // [2][2][256][32]
  u16* sB = smem + 32768;                          // [2][2][256][32]
  float* rowsum = (float*)(smem + 65536);          // [4][256] (MODE 1)

  // bijective XCD swizzle (guarded for tiny grids)
  const int nwg = gridDim.x;
  const int qq = nwg >> 3;
  const int wg = (nwg & 7) ? (int)blockIdx.x
                           : ((blockIdx.x & 7) * qq + (blockIdx.x >> 3));
  const int nb = wg & 3;
  const int mb = wg >> 2;

  const int tid = threadIdx.x;
  const int wave = tid >> 6, lane = tid & 63;
  const int wm = wave >> 2, wn = wave & 3;    // 2 row-halves x 4 col-quarters

  // staging addressing (rule-21 pair: inverse-swizzled global source, linear LDS)
  const int l4 = lane >> 2, ls = lane & 3;
  const int fsw  = (l4 >> 1) & 3;
  const int koff = ((ls ^ fsw) << 3);

  const u16* gAh0 = Ahi + (size_t)(mb*256 + wave*32 + l4) * K + koff;
  const u16* gAh1 = gAh0 + (size_t)16 * K;
  const u16* gAl0 = Alo + (size_t)(mb*256 + wave*32 + l4) * K + koff;
  const u16* gAl1 = gAl0 + (size_t)16 * K;
  const u16* gBh0 = Bhi + (size_t)(nb*256 + wave*32 + l4) * K + koff;
  const u16* gBh1 = gBh0 + (size_t)16 * K;
  const u16* gBl0 = Blo + (size_t)(nb*256 + wave*32 + l4) * K + koff;
  const u16* gBl1 = gBl0 + (size_t)16 * K;

  // fragment addressing (swizzled ds_read)
  const int r16 = lane & 15, g = lane >> 4;
  const int fr   = (r16 >> 1) & 3;
  const int slot = ((g ^ fr) << 3);

  f32x4 acc[8][4];
#pragma unroll
  for (int m = 0; m < 8; m++)
#pragma unroll
    for (int n = 0; n < 4; n++)
      acc[m][n] = (f32x4){0.f, 0.f, 0.f, 0.f};

  const int NT = K >> 5;          // 24 or 32
  // prologue: stage tile 0, drain, sync
  STAGE_A1(0); STAGE_A2(0); STAGE_B1(0); STAGE_B2(0);
  asm volatile("s_waitcnt vmcnt(0)\n\ts_barrier" ::: "memory");

#pragma unroll 1
  for (int t = 0; t < NT; ++t){
    const int cur = t & 1, nxt = cur ^ 1;
    const u16* pA = sA + cur*16384;
    const u16* pB = sB + cur*16384;
    const bool pf = (t + 1 < NT);
    bf16x8 ah[8], al[4], bh[4], bl[4];

    // ---- P1: read bh + ah0-3 ; prefetch next A ----
#pragma unroll
    for (int n = 0; n < 4; n++) bh[n] = *(const bf16x8*)(pB + (wn*64 + n*16 + r16)*32 + slot);
#pragma unroll
    for (int m = 0; m < 4; m++) ah[m] = *(const bf16x8*)(pA + (wm*128 + m*16 + r16)*32 + slot);
    if (pf){ STAGE_A1(nxt); STAGE_A2(nxt); }
    BARRIER(); LGKM0();
    CLUSTER(ah, 0, bh);
    BARRIER();

    // ---- P2: read ah4-7 ; prefetch next B ----
#pragma unroll
    for (int m = 0; m < 4; m++) ah[4+m] = *(const bf16x8*)(pA + (wm*128 + (4+m)*16 + r16)*32 + slot);
    if (pf){ STAGE_B1(nxt); STAGE_B2(nxt); }
    BARRIER(); LGKM0();
    CLUSTER(ah+4, 4, bh);
    BARRIER();

    // ---- P3: read al0-3 ----
#pragma unroll
    for (int m = 0; m < 4; m++) al[m] = *(const bf16x8*)(pA + 8192 + (wm*128 + m*16 + r16)*32 + slot);
    BARRIER(); LGKM0();
    CLUSTER(al, 0, bh);
    BARRIER();

    // ---- P4: read al4-7 (reuse regs) ----
#pragma unroll
    for (int m = 0; m < 4; m++) al[m] = *(const bf16x8*)(pA + 8192 + (wm*128 + (4+m)*16 + r16)*32 + slot);
    BARRIER(); LGKM0();
    CLUSTER(al, 4, bh);
    BARRIER();

    // ---- P5: read bl ----
#pragma unroll
    for (int n = 0; n < 4; n++) bl[n] = *(const bf16x8*)(pB + 8192 + (wn*64 + n*16 + r16)*32 + slot);
    BARRIER(); LGKM0();
    CLUSTER(ah, 0, bl);
    BARRIER();

    // ---- P6: regs only ; closing waits next tile's loads ----
    CLUSTER(ah+4, 4, bl);
    if (pf){
      asm volatile("s_waitcnt vmcnt(0)\n\ts_barrier" ::: "memory");
    } else {
      BARRIER();
    }
  }

  if constexpr (MODE == 0){
#pragma unroll
    for (int n = 0; n < 4; n++){
      int col = nb*256 + wn*64 + n*16 + r16;
      float bv = bias[col];
#pragma unroll
      for (int m = 0; m < 8; m++){
        int rbase = mb*256 + wm*128 + m*16 + g*4;
#pragma unroll
        for (int q = 0; q < 4; q++){
          float val = acc[m][n][q] + bv;
          val = val * val;
          u16 hi = f2bf(val);
          u16 lo = f2bf(val - bf2f(hi));
          size_t oi = (size_t)(rbase + q) * 1024 + col;
          Oh[oi] = hi; Ol[oi] = lo;
        }
      }
    }
  } else {
    float w3v[4], bv[4];
#pragma unroll
    for (int n = 0; n < 4; n++){
      int col = nb*256 + wn*64 + n*16 + r16;
      w3v[n] = W3[col];
      bv[n]  = bias[col];
    }
    float rp[8][4];
#pragma unroll
    for (int m = 0; m < 8; m++)
#pragma unroll
      for (int q = 0; q < 4; q++)
        rp[m][q] = 0.f;
#pragma unroll
    for (int m = 0; m < 8; m++)
#pragma unroll
      for (int n = 0; n < 4; n++)
#pragma unroll
        for (int q = 0; q < 4; q++){
          float v = acc[m][n][q] + bv[n];
          rp[m][q] += v * v * w3v[n];
        }
#pragma unroll
    for (int m = 0; m < 8; m++)
#pragma unroll
      for (int q = 0; q < 4; q++){
        float s = rp[m][q];
        s += __shfl_xor(s, 1); s += __shfl_xor(s, 2);
        s += __shfl_xor(s, 4); s += __shfl_xor(s, 8);
        rp[m][q] = s;
      }
    if (r16 == 0){
#pragma unroll
      for (int m = 0; m < 8; m++)
#pragma unroll
        for (int q = 0; q < 4; q++)
          rowsum[wn*256 + wm*128 + m*16 + g*4 + q] = rp[m][q];
    }
    __syncthreads();
    if (tid < 256){
      float s = rowsum[tid] + rowsum[256 + tid] + rowsum[512 + tid] + rowsum[768 + tid];
      P[(size_t)nb * Pstride + mb*256 + tid] = s;
    }
  }
}

// ---------------------------------------------------------------------------
// finalize: a3 = b3 + sum_j partial[j][row]; out = clip(2log|a3a|*Wfa - ..b..)
// ---------------------------------------------------------------------------
__global__ void finalize_kernel(const float* __restrict__ Pa, const float* __restrict__ Pb,
                                int Pstride,
                                const float* __restrict__ b3a, const float* __restrict__ Wfa,
                                const float* __restrict__ b3b, const float* __restrict__ Wfb,
                                float* __restrict__ out, int row0, int Rc)
{
  int r = blockIdx.x * 256 + threadIdx.x;
  if (r >= Rc) return;
  float sa = b3a[0], sb = b3b[0];
#pragma unroll
  for (int j = 0; j < 4; j++){
    sa += Pa[(size_t)j * Pstride + r];
    sb += Pb[(size_t)j * Pstride + r];
  }
  float ta = 2.f * logf(fabsf(sa)) * Wfa[0];
  float tb = 2.f * logf(fabsf(sb)) * Wfb[0];
  float o = ta - tb;
  o = fminf(fmaxf(o, -1000000.f), 1000000.f);
  out[row0 + r] = o;
}

// ---------------------------------------------------------------------------
static inline size_t align256(size_t v){ return (v + 255) & ~(size_t)255; }

extern "C" void kernel_launch(void* const* d_in, const int* in_sizes, int n_in,
                              void* d_out, int out_size, void* d_ws, size_t ws_size,
                              hipStream_t stream)
{
  (void)n_in; (void)out_size;
  const float* x   = (const float*)d_in[0];
  const float* W1a = (const float*)d_in[1];
  const float* b1a = (const float*)d_in[2];
  const float* W2a = (const float*)d_in[3];
  const float* b2a = (const float*)d_in[4];
  const float* W3a = (const float*)d_in[5];
  const float* b3a = (const float*)d_in[6];
  const float* Wfa = (const float*)d_in[7];
  const float* W1b = (const float*)d_in[8];
  const float* b1b = (const float*)d_in[9];
  const float* W2b = (const float*)d_in[10];
  const float* b2b = (const float*)d_in[11];
  const float* W3b = (const float*)d_in[12];
  const float* b3b = (const float*)d_in[13];
  const float* Wfb = (const float*)d_in[14];
  float* out = (float*)d_out;

  const int B  = in_sizes[0] / 18;
  const int K1 = 768;
  const int K2 = 1024;

  hipFuncSetAttribute((const void*)gemm_k<0>,
                      hipFuncAttributeMaxDynamicSharedMemorySize, GEMM_SMEM_BYTES);
  hipFuncSetAttribute((const void*)gemm_k<1>,
                      hipFuncAttributeMaxDynamicSharedMemorySize, GEMM_SMEM_BYTES);

  char* base = (char*)d_ws;
  size_t off = 0;
  auto carve = [&](size_t bytes) -> char* {
    off = align256(off);
    char* p = base + off;
    off += bytes;
    return p;
  };

  u16* wt1ah = (u16*)carve((size_t)1024 * K1 * 2);
  u16* wt1al = (u16*)carve((size_t)1024 * K1 * 2);
  u16* wt2ah = (u16*)carve((size_t)1024 * K2 * 2);
  u16* wt2al = (u16*)carve((size_t)1024 * K2 * 2);
  u16* wt1bh = (u16*)carve((size_t)1024 * K1 * 2);
  u16* wt1bl = (u16*)carve((size_t)1024 * K1 * 2);
  u16* wt2bh = (u16*)carve((size_t)1024 * K2 * 2);
  u16* wt2bl = (u16*)carve((size_t)1024 * K2 * 2);

  size_t fixed = align256(off);
  // per-row live set: feats hi+lo (3072) + ONE tower's h1 hi+lo (4096) + partials (32)
  const long long per_row = (long long)K1*4 + 4096 + 32;
  long long avail = (long long)ws_size - (long long)fixed - 8192;
  long long rmax = avail > 0 ? avail / per_row : 0;
  int R = (int)((rmax / 256) * 256);
  if (R > B) R = B;
  if (R < 256) R = 256;

  u16* fh   = (u16*)carve((size_t)R * K1 * 2);
  u16* fl   = (u16*)carve((size_t)R * K1 * 2);
  u16* h1h  = (u16*)carve((size_t)R * 1024 * 2);   // reused by both towers
  u16* h1l  = (u16*)carve((size_t)R * 1024 * 2);
  float* pa = (float*)carve((size_t)4 * R * 4);
  float* pb = (float*)carve((size_t)4 * R * 4);

  // all four weight transposes in one dispatch
  wconv_kernel<<<dim3(32, 32, 4), 256, 0, stream>>>(
      W1a, wt1ah, wt1al, K1,
      W2a, wt2ah, wt2al, K2,
      W1b, wt1bh, wt1bl, K1,
      W2b, wt2bh, wt2bl, K2);

  for (int row0 = 0; row0 < B; row0 += R){
    int Rc = B - row0; if (Rc > R) Rc = R;
    int MB = Rc / 256;
    feats_kernel<<<Rc/8, 256, 0, stream>>>(x, fh, fl, row0);
    // tower a
    gemm_k<0><<<dim3(4*MB), 512, GEMM_SMEM_BYTES, stream>>>(
        fh, fl, wt1ah, wt1al, b1a, h1h, h1l, nullptr, nullptr, 0, K1);
    gemm_k<1><<<dim3(4*MB), 512, GEMM_SMEM_BYTES, stream>>>(
        h1h, h1l, wt2ah, wt2al, b2a, nullptr, nullptr, W3a, pa, R, K2);
    // tower b (reuses h1 buffers)
    gemm_k<0><<<dim3(4*MB), 512, GEMM_SMEM_BYTES, stream>>>(
        fh, fl, wt1bh, wt1bl, b1b, h1h, h1l, nullptr, nullptr, 0, K1);
    gemm_k<1><<<dim3(4*MB), 512, GEMM_SMEM_BYTES, stream>>>(
        h1h, h1l, wt2bh, wt2bl, b2b, nullptr, nullptr, W3b, pb, R, K2);
    finalize_kernel<<<(Rc + 255)/256, 256, 0, stream>>>(pa, pb, R, b3a, Wfa, b3b, Wfb,
                                                        out, row0, Rc);
  }
}

// Round 9
// 439.941 us; speedup vs baseline: 2.1164x; 1.5357x over previous
//
#include <hip/hip_runtime.h>

typedef unsigned short u16;
typedef unsigned int u32;
typedef __attribute__((ext_vector_type(8))) short bf16x8;
typedef __attribute__((ext_vector_type(4))) float f32x4;

__device__ __forceinline__ u16 f2bf(float x){
  unsigned u = __builtin_bit_cast(unsigned, x);
  unsigned r = (u + 0x7FFFu + ((u >> 16) & 1u)) >> 16;   // RNE
  return (u16)r;
}
__device__ __forceinline__ float bf2f(u16 h){
  unsigned u = ((unsigned)h) << 16;
  return __builtin_bit_cast(float, u);
}

__device__ __forceinline__ void gld_lds16(const void* g, void* l){
  __builtin_amdgcn_global_load_lds((const __attribute__((address_space(1))) void*)g,
                                   (__attribute__((address_space(3))) void*)l,
                                   16, 0, 0);
}

// ---------------------------------------------------------------------------
// Weight transpose + bf16 hi/lo split, 4 jobs in one dispatch (blockIdx.z).
// B-side keeps hi+lo (2-pass split precision lives on the weight side).
// ---------------------------------------------------------------------------
__global__ void wconv_kernel(const float* __restrict__ W0, u16* __restrict__ Th0, u16* __restrict__ Tl0, int K0p,
                             const float* __restrict__ W1, u16* __restrict__ Th1, u16* __restrict__ Tl1, int K1p,
                             const float* __restrict__ W2, u16* __restrict__ Th2, u16* __restrict__ Tl2, int K2p,
                             const float* __restrict__ W3, u16* __restrict__ Th3, u16* __restrict__ Tl3, int K3p)
{
  __shared__ float t[32][33];
  int z = blockIdx.z;
  const float* W = z==0 ? W0 : z==1 ? W1 : z==2 ? W2 : W3;
  u16* Th = z==0 ? Th0 : z==1 ? Th1 : z==2 ? Th2 : Th3;
  u16* Tl = z==0 ? Tl0 : z==1 ? Tl1 : z==2 ? Tl2 : Tl3;
  int Kpad = z==0 ? K0p : z==1 ? K1p : z==2 ? K2p : K3p;
  int K = (Kpad == 768) ? 729 : 1024;
  int k0 = blockIdx.x * 32;
  if (k0 >= Kpad) return;
  int n0 = blockIdx.y * 32;
  int tx = threadIdx.x & 31, ty = threadIdx.x >> 5;
#pragma unroll
  for (int j = 0; j < 4; j++){
    int k = k0 + ty + j*8;
    float v = (k < K) ? W[(size_t)k*1024 + (n0 + tx)] : 0.f;
    t[ty + j*8][tx] = v;
  }
  __syncthreads();
#pragma unroll
  for (int j = 0; j < 4; j++){
    int n = n0 + ty + j*8;
    int k = k0 + tx;
    float v = t[tx][ty + j*8];
    u16 hi = f2bf(v);
    u16 lo = f2bf(v - bf2f(hi));
    size_t idx = (size_t)n*Kpad + k;
    Th[idx] = hi; Tl[idx] = lo;
  }
}

// ---------------------------------------------------------------------------
// feats, LUT-restructured (R6 form); now writes bf16 HI only (A-side lo
// dropped by the 2-pass scheme).
// ---------------------------------------------------------------------------
__global__ void feats_kernel(const float* __restrict__ x,
                             u16* __restrict__ fh,
                             int row0)
{
  __shared__ float cC[8][28];
  __shared__ float tA[8][81];
  __shared__ float tB[8][12];
  __shared__ float ivk[8];
  const int tid = threadIdx.x;
  const int lrow0 = blockIdx.x * 8;
  if (tid < 8){
    const float* xr = x + (size_t)(row0 + lrow0 + tid) * 18;
    float kk = 1.f;
#pragma unroll
    for (int f = 0; f < 3; f++){
      float xa = xr[3*f+0], xb = xr[3*f+1], xc = xr[3*f+2];
      float ya = xr[9+3*f+0], yb = xr[9+3*f+1], yc = xr[9+3*f+2];
      int bse = f * 9;
      cC[tid][bse+0] = xa*xa + ya*ya;
      cC[tid][bse+1] = xa*xb + ya*yb;
      cC[tid][bse+2] = xa*xc + ya*yc;
      cC[tid][bse+3] = xb*xb + yb*yb;
      cC[tid][bse+4] = xb*xc + yb*yc;
      cC[tid][bse+5] = xc*xc + yc*yc;
      cC[tid][bse+6] = xa*yb - xb*ya;
      cC[tid][bse+7] = xa*yc - xc*ya;
      cC[tid][bse+8] = xb*yc - xc*yb;
      kk *= (xa*xa+ya*ya + xb*xb+yb*yb + xc*xc+yc*yc);
    }
    ivk[tid] = 1.f / kk;
#pragma unroll
    for (int j = 0; j < 6; j++) tB[tid][j] = cC[tid][18+j];
#pragma unroll
    for (int j = 0; j < 3; j++) tB[tid][6+j] = cC[tid][24+j];
  }
  __syncthreads();
#pragma unroll 1
  for (int e = tid; e < 648; e += 256){
    int r = e / 81;
    int k = e - r*81;
    const float* cc = cC[r];
    float val;
    if (k < 36)      {               val =   cc[k/6]     * cc[9  + k%6]; }
    else if (k < 45) { int u = k-36; val = -(cc[6 + u/3] * cc[15 + u%3]); }
    else if (k < 63) { int u = k-45; val =   cc[u/3]     * cc[15 + u%3]; }
    else             { int u = k-63; val = -(cc[6 + u/6] * cc[9  + u%6]); }
    tA[r][k] = val;
  }
  __syncthreads();
#pragma unroll 1
  for (int jj = 0; jj < 3; jj++){
    int o = jj*256 + tid;
    int idxA = 0, idxB = 0; float sgn = 0.f;
    if (o < 270)      {              idxA = o/6;      idxB = o - (o/6)*6; sgn =  1.f; }
    else if (o < 378) { int t = o-270; idxA = 45 + t/3; idxB = 6 + t%3;   sgn = -1.f; }
    else if (o < 513) { int t = o-378; idxA = t/3;      idxB = 6 + t%3;   sgn =  1.f; }
    else if (o < 729) { int t = o-513; idxA = 45 + t/6; idxB = t%6;       sgn = -1.f; }
#pragma unroll
    for (int r = 0; r < 8; r++){
      float v = sgn * tA[r][idxA] * tB[r][idxB] * ivk[r];
      size_t oi = (size_t)(lrow0 + r) * 768 + o;
      fh[oi] = f2bf(v);
    }
  }
}

// ---------------------------------------------------------------------------
// Single-tower GEMM, 2-pass split precision: C = Ahi*Bhi + Ahi*Blo
// (A-side lo dropped; B = transposed weights keeps hi+lo).
// 256x256 block tile, BK=32, 512 threads = 8 waves, wave tile 128x64.
// 4-phase K-loop {ds_read ; prefetch ; barrier ; lgkmcnt(0) ; 16 MFMA ;
// barrier}; closing vmcnt(0) once per tile.
// MODE 0: epilogue (acc+bias)^2 -> bf16 hi only (layer 1)
// MODE 1: epilogue (acc+bias)^2 * W3[col], block-col reduce -> partial (layer 2)
// LDS: sA[2][256][32] (32KB) + sB[2][2][256][32] (64KB) + rowsum (4KB)
// ---------------------------------------------------------------------------
#define GEMM_SMEM_BYTES ((2*8192 + 2*16384)*2 + 4*256*4)

#define STAGE_A(BUF)  do{ u16* _a = sA + (BUF)*8192; \
    gld_lds16(gAh0, _a + wave*1024); gld_lds16(gAh1, _a + wave*1024 + 512); \
    gAh0 += 32; gAh1 += 32; }while(0)
#define STAGE_BH(BUF) do{ u16* _b = sB + (BUF)*16384; \
    gld_lds16(gBh0, _b + wave*1024); gld_lds16(gBh1, _b + wave*1024 + 512); \
    gBh0 += 32; gBh1 += 32; }while(0)
#define STAGE_BL(BUF) do{ u16* _b = sB + (BUF)*16384 + 8192; \
    gld_lds16(gBl0, _b + wave*1024); gld_lds16(gBl1, _b + wave*1024 + 512); \
    gBl0 += 32; gBl1 += 32; }while(0)

#define BARRIER()  asm volatile("s_barrier" ::: "memory")
#define LGKM0()    asm volatile("s_waitcnt lgkmcnt(0)" ::: "memory")

#define CLUSTER(A, O, B) do{ \
    __builtin_amdgcn_s_setprio(1); \
    _Pragma("unroll") for (int m_ = 0; m_ < 4; m_++) \
      _Pragma("unroll") for (int n_ = 0; n_ < 4; n_++) \
        acc[(O)+m_][n_] = __builtin_amdgcn_mfma_f32_16x16x32_bf16((A)[m_], (B)[n_], acc[(O)+m_][n_], 0, 0, 0); \
    __builtin_amdgcn_s_setprio(0); \
  }while(0)

template<int MODE>
__global__ __launch_bounds__(512, 1) void gemm_k(
    const u16* __restrict__ Ahi,
    const u16* __restrict__ Bhi, const u16* __restrict__ Blo,
    const float* __restrict__ bias,
    u16* __restrict__ Oh,
    const float* __restrict__ W3, float* __restrict__ P, int Pstride,
    int K)
{
  extern __shared__ __align__(16) u16 smem[];
  u16* sA = smem;                                  // [2][256][32]
  u16* sB = smem + 16384;                          // [2][2][256][32]
  float* rowsum = (float*)(smem + 49152);          // [4][256] (MODE 1)

  // bijective XCD swizzle (guarded for tiny grids)
  const int nwg = gridDim.x;
  const int qq = nwg >> 3;
  const int wg = (nwg & 7) ? (int)blockIdx.x
                           : ((blockIdx.x & 7) * qq + (blockIdx.x >> 3));
  const int nb = wg & 3;
  const int mb = wg >> 2;

  const int tid = threadIdx.x;
  const int wave = tid >> 6, lane = tid & 63;
  const int wm = wave >> 2, wn = wave & 3;    // 2 row-halves x 4 col-quarters

  // staging addressing (rule-21 pair: inverse-swizzled global source, linear LDS)
  const int l4 = lane >> 2, ls = lane & 3;
  const int fsw  = (l4 >> 1) & 3;
  const int koff = ((ls ^ fsw) << 3);

  const u16* gAh0 = Ahi + (size_t)(mb*256 + wave*32 + l4) * K + koff;
  const u16* gAh1 = gAh0 + (size_t)16 * K;
  const u16* gBh0 = Bhi + (size_t)(nb*256 + wave*32 + l4) * K + koff;
  const u16* gBh1 = gBh0 + (size_t)16 * K;
  const u16* gBl0 = Blo + (size_t)(nb*256 + wave*32 + l4) * K + koff;
  const u16* gBl1 = gBl0 + (size_t)16 * K;

  // fragment addressing (swizzled ds_read)
  const int r16 = lane & 15, g = lane >> 4;
  const int fr   = (r16 >> 1) & 3;
  const int slot = ((g ^ fr) << 3);

  f32x4 acc[8][4];
#pragma unroll
  for (int m = 0; m < 8; m++)
#pragma unroll
    for (int n = 0; n < 4; n++)
      acc[m][n] = (f32x4){0.f, 0.f, 0.f, 0.f};

  const int NT = K >> 5;          // 24 or 32
  STAGE_A(0); STAGE_BH(0); STAGE_BL(0);
  asm volatile("s_waitcnt vmcnt(0)\n\ts_barrier" ::: "memory");

#pragma unroll 1
  for (int t = 0; t < NT; ++t){
    const int cur = t & 1, nxt = cur ^ 1;
    const u16* pA = sA + cur*8192;
    const u16* pB = sB + cur*16384;
    const bool pf = (t + 1 < NT);
    bf16x8 ah[8], bh[4], bl[4];

    // ---- P1: read bh + ah0-3 ; prefetch next A ----
#pragma unroll
    for (int n = 0; n < 4; n++) bh[n] = *(const bf16x8*)(pB + (wn*64 + n*16 + r16)*32 + slot);
#pragma unroll
    for (int m = 0; m < 4; m++) ah[m] = *(const bf16x8*)(pA + (wm*128 + m*16 + r16)*32 + slot);
    if (pf){ STAGE_A(nxt); }
    BARRIER(); LGKM0();
    CLUSTER(ah, 0, bh);
    BARRIER();

    // ---- P2: read ah4-7 ; prefetch next Bh ----
#pragma unroll
    for (int m = 0; m < 4; m++) ah[4+m] = *(const bf16x8*)(pA + (wm*128 + (4+m)*16 + r16)*32 + slot);
    if (pf){ STAGE_BH(nxt); }
    BARRIER(); LGKM0();
    CLUSTER(ah+4, 4, bh);
    BARRIER();

    // ---- P3: read bl ; prefetch next Bl ----
#pragma unroll
    for (int n = 0; n < 4; n++) bl[n] = *(const bf16x8*)(pB + 8192 + (wn*64 + n*16 + r16)*32 + slot);
    if (pf){ STAGE_BL(nxt); }
    BARRIER(); LGKM0();
    CLUSTER(ah, 0, bl);
    BARRIER();

    // ---- P4: regs only ; closing waits next tile's 6 loads ----
    CLUSTER(ah+4, 4, bl);
    if (pf){
      asm volatile("s_waitcnt vmcnt(0)\n\ts_barrier" ::: "memory");
    } else {
      BARRIER();
    }
  }

  if constexpr (MODE == 0){
#pragma unroll
    for (int n = 0; n < 4; n++){
      int col = nb*256 + wn*64 + n*16 + r16;
      float bv = bias[col];
#pragma unroll
      for (int m = 0; m < 8; m++){
        int rbase = mb*256 + wm*128 + m*16 + g*4;
#pragma unroll
        for (int q = 0; q < 4; q++){
          float val = acc[m][n][q] + bv;
          val = val * val;
          size_t oi = (size_t)(rbase + q) * 1024 + col;
          Oh[oi] = f2bf(val);
        }
      }
    }
  } else {
    float w3v[4], bv[4];
#pragma unroll
    for (int n = 0; n < 4; n++){
      int col = nb*256 + wn*64 + n*16 + r16;
      w3v[n] = W3[col];
      bv[n]  = bias[col];
    }
    float rp[8][4];
#pragma unroll
    for (int m = 0; m < 8; m++)
#pragma unroll
      for (int q = 0; q < 4; q++)
        rp[m][q] = 0.f;
#pragma unroll
    for (int m = 0; m < 8; m++)
#pragma unroll
      for (int n = 0; n < 4; n++)
#pragma unroll
        for (int q = 0; q < 4; q++){
          float v = acc[m][n][q] + bv[n];
          rp[m][q] += v * v * w3v[n];
        }
#pragma unroll
    for (int m = 0; m < 8; m++)
#pragma unroll
      for (int q = 0; q < 4; q++){
        float s = rp[m][q];
        s += __shfl_xor(s, 1); s += __shfl_xor(s, 2);
        s += __shfl_xor(s, 4); s += __shfl_xor(s, 8);
        rp[m][q] = s;
      }
    if (r16 == 0){
#pragma unroll
      for (int m = 0; m < 8; m++)
#pragma unroll
        for (int q = 0; q < 4; q++)
          rowsum[wn*256 + wm*128 + m*16 + g*4 + q] = rp[m][q];
    }
    __syncthreads();
    if (tid < 256){
      float s = rowsum[tid] + rowsum[256 + tid] + rowsum[512 + tid] + rowsum[768 + tid];
      P[(size_t)nb * Pstride + mb*256 + tid] = s;
    }
  }
}

// ---------------------------------------------------------------------------
// finalize: a3 = b3 + sum_j partial[j][row]; out = clip(2log|a3a|*Wfa - ..b..)
// ---------------------------------------------------------------------------
__global__ void finalize_kernel(const float* __restrict__ Pa, const float* __restrict__ Pb,
                                int Pstride,
                                const float* __restrict__ b3a, const float* __restrict__ Wfa,
                                const float* __restrict__ b3b, const float* __restrict__ Wfb,
                                float* __restrict__ out, int row0, int Rc)
{
  int r = blockIdx.x * 256 + threadIdx.x;
  if (r >= Rc) return;
  float sa = b3a[0], sb = b3b[0];
#pragma unroll
  for (int j = 0; j < 4; j++){
    sa += Pa[(size_t)j * Pstride + r];
    sb += Pb[(size_t)j * Pstride + r];
  }
  float ta = 2.f * logf(fabsf(sa)) * Wfa[0];
  float tb = 2.f * logf(fabsf(sb)) * Wfb[0];
  float o = ta - tb;
  o = fminf(fmaxf(o, -1000000.f), 1000000.f);
  out[row0 + r] = o;
}

// ---------------------------------------------------------------------------
static inline size_t align256(size_t v){ return (v + 255) & ~(size_t)255; }

extern "C" void kernel_launch(void* const* d_in, const int* in_sizes, int n_in,
                              void* d_out, int out_size, void* d_ws, size_t ws_size,
                              hipStream_t stream)
{
  (void)n_in; (void)out_size;
  const float* x   = (const float*)d_in[0];
  const float* W1a = (const float*)d_in[1];
  const float* b1a = (const float*)d_in[2];
  const float* W2a = (const float*)d_in[3];
  const float* b2a = (const float*)d_in[4];
  const float* W3a = (const float*)d_in[5];
  const float* b3a = (const float*)d_in[6];
  const float* Wfa = (const float*)d_in[7];
  const float* W1b = (const float*)d_in[8];
  const float* b1b = (const float*)d_in[9];
  const float* W2b = (const float*)d_in[10];
  const float* b2b = (const float*)d_in[11];
  const float* W3b = (const float*)d_in[12];
  const float* b3b = (const float*)d_in[13];
  const float* Wfb = (const float*)d_in[14];
  float* out = (float*)d_out;

  const int B  = in_sizes[0] / 18;
  const int K1 = 768;
  const int K2 = 1024;

  hipFuncSetAttribute((const void*)gemm_k<0>,
                      hipFuncAttributeMaxDynamicSharedMemorySize, GEMM_SMEM_BYTES);
  hipFuncSetAttribute((const void*)gemm_k<1>,
                      hipFuncAttributeMaxDynamicSharedMemorySize, GEMM_SMEM_BYTES);

  char* base = (char*)d_ws;
  size_t off = 0;
  auto carve = [&](size_t bytes) -> char* {
    off = align256(off);
    char* p = base + off;
    off += bytes;
    return p;
  };

  u16* wt1ah = (u16*)carve((size_t)1024 * K1 * 2);
  u16* wt1al = (u16*)carve((size_t)1024 * K1 * 2);
  u16* wt2ah = (u16*)carve((size_t)1024 * K2 * 2);
  u16* wt2al = (u16*)carve((size_t)1024 * K2 * 2);
  u16* wt1bh = (u16*)carve((size_t)1024 * K1 * 2);
  u16* wt1bl = (u16*)carve((size_t)1024 * K1 * 2);
  u16* wt2bh = (u16*)carve((size_t)1024 * K2 * 2);
  u16* wt2bl = (u16*)carve((size_t)1024 * K2 * 2);

  size_t fixed = align256(off);
  // per-row live set: feats hi (1536) + one tower's h1 hi (2048) + partials (32)
  const long long per_row = (long long)K1*2 + 2048 + 32;
  long long avail = (long long)ws_size - (long long)fixed - 8192;
  long long rmax = avail > 0 ? avail / per_row : 0;
  int R = (int)((rmax / 256) * 256);
  if (R > B) R = B;
  if (R < 256) R = 256;

  u16* fh  = (u16*)carve((size_t)R * K1 * 2);
  u16* h1h = (u16*)carve((size_t)R * 1024 * 2);   // reused by both towers
  float* pa = (float*)carve((size_t)4 * R * 4);
  float* pb = (float*)carve((size_t)4 * R * 4);

  // all four weight transposes in one dispatch
  wconv_kernel<<<dim3(32, 32, 4), 256, 0, stream>>>(
      W1a, wt1ah, wt1al, K1,
      W2a, wt2ah, wt2al, K2,
      W1b, wt1bh, wt1bl, K1,
      W2b, wt2bh, wt2bl, K2);

  for (int row0 = 0; row0 < B; row0 += R){
    int Rc = B - row0; if (Rc > R) Rc = R;
    int MB = Rc / 256;
    feats_kernel<<<Rc/8, 256, 0, stream>>>(x, fh, row0);
    // tower a
    gemm_k<0><<<dim3(4*MB), 512, GEMM_SMEM_BYTES, stream>>>(
        fh, wt1ah, wt1al, b1a, h1h, nullptr, nullptr, 0, K1);
    gemm_k<1><<<dim3(4*MB), 512, GEMM_SMEM_BYTES, stream>>>(
        h1h, wt2ah, wt2al, b2a, nullptr, W3a, pa, R, K2);
    // tower b (reuses h1 buffer)
    gemm_k<0><<<dim3(4*MB), 512, GEMM_SMEM_BYTES, stream>>>(
        fh, wt1bh, wt1bl, b1b, h1h, nullptr, nullptr, 0, K1);
    gemm_k<1><<<dim3(4*MB), 512, GEMM_SMEM_BYTES, stream>>>(
        h1h, wt2bh, wt2bl, b2b, nullptr, W3b, pb, R, K2);
    finalize_kernel<<<(Rc + 255)/256, 256, 0, stream>>>(pa, pb, R, b3a, Wfa, b3b, Wfb,
                                                        out, row0, Rc);
  }
}

// Round 10
// 308.509 us; speedup vs baseline: 3.0181x; 1.4260x over previous
//
#include <hip/hip_runtime.h>

typedef unsigned short u16;
typedef unsigned int u32;
typedef __attribute__((ext_vector_type(8))) short bf16x8;
typedef __attribute__((ext_vector_type(4))) float f32x4;

__device__ __forceinline__ u16 f2bf(float x){
  unsigned u = __builtin_bit_cast(unsigned, x);
  unsigned r = (u + 0x7FFFu + ((u >> 16) & 1u)) >> 16;   // RNE
  return (u16)r;
}
__device__ __forceinline__ float bf2f(u16 h){
  unsigned u = ((unsigned)h) << 16;
  return __builtin_bit_cast(float, u);
}

__device__ __forceinline__ void gld_lds16(const void* g, void* l){
  __builtin_amdgcn_global_load_lds((const __attribute__((address_space(1))) void*)g,
                                   (__attribute__((address_space(3))) void*)l,
                                   16, 0, 0);
}

// ---------------------------------------------------------------------------
// Weight transpose + bf16 cast, 4 jobs in one dispatch (blockIdx.z).
// W[K][1024] -> WT [1024][Kpad] (bf16 hi only), rows k>=K zero-padded.
// ---------------------------------------------------------------------------
__global__ void wconv_kernel(const float* __restrict__ W0, u16* __restrict__ Th0, int K0p,
                             const float* __restrict__ W1, u16* __restrict__ Th1, int K1p,
                             const float* __restrict__ W2, u16* __restrict__ Th2, int K2p,
                             const float* __restrict__ W3, u16* __restrict__ Th3, int K3p)
{
  __shared__ float t[32][33];
  int z = blockIdx.z;
  const float* W = z==0 ? W0 : z==1 ? W1 : z==2 ? W2 : W3;
  u16* Th = z==0 ? Th0 : z==1 ? Th1 : z==2 ? Th2 : Th3;
  int Kpad = z==0 ? K0p : z==1 ? K1p : z==2 ? K2p : K3p;
  int K = (Kpad == 768) ? 729 : 1024;
  int k0 = blockIdx.x * 32;
  if (k0 >= Kpad) return;
  int n0 = blockIdx.y * 32;
  int tx = threadIdx.x & 31, ty = threadIdx.x >> 5;
#pragma unroll
  for (int j = 0; j < 4; j++){
    int k = k0 + ty + j*8;
    float v = (k < K) ? W[(size_t)k*1024 + (n0 + tx)] : 0.f;
    t[ty + j*8][tx] = v;
  }
  __syncthreads();
#pragma unroll
  for (int j = 0; j < 4; j++){
    int n = n0 + ty + j*8;
    int k = k0 + tx;
    size_t idx = (size_t)n*Kpad + k;
    Th[idx] = f2bf(t[tx][ty + j*8]);
  }
}

// ---------------------------------------------------------------------------
// feats, LUT-restructured (R6 form); writes bf16 hi only.
// ---------------------------------------------------------------------------
__global__ void feats_kernel(const float* __restrict__ x,
                             u16* __restrict__ fh,
                             int row0)
{
  __shared__ float cC[8][28];
  __shared__ float tA[8][81];
  __shared__ float tB[8][12];
  __shared__ float ivk[8];
  const int tid = threadIdx.x;
  const int lrow0 = blockIdx.x * 8;
  if (tid < 8){
    const float* xr = x + (size_t)(row0 + lrow0 + tid) * 18;
    float kk = 1.f;
#pragma unroll
    for (int f = 0; f < 3; f++){
      float xa = xr[3*f+0], xb = xr[3*f+1], xc = xr[3*f+2];
      float ya = xr[9+3*f+0], yb = xr[9+3*f+1], yc = xr[9+3*f+2];
      int bse = f * 9;
      cC[tid][bse+0] = xa*xa + ya*ya;
      cC[tid][bse+1] = xa*xb + ya*yb;
      cC[tid][bse+2] = xa*xc + ya*yc;
      cC[tid][bse+3] = xb*xb + yb*yb;
      cC[tid][bse+4] = xb*xc + yb*yc;
      cC[tid][bse+5] = xc*xc + yc*yc;
      cC[tid][bse+6] = xa*yb - xb*ya;
      cC[tid][bse+7] = xa*yc - xc*ya;
      cC[tid][bse+8] = xb*yc - xc*yb;
      kk *= (xa*xa+ya*ya + xb*xb+yb*yb + xc*xc+yc*yc);
    }
    ivk[tid] = 1.f / kk;
#pragma unroll
    for (int j = 0; j < 6; j++) tB[tid][j] = cC[tid][18+j];
#pragma unroll
    for (int j = 0; j < 3; j++) tB[tid][6+j] = cC[tid][24+j];
  }
  __syncthreads();
#pragma unroll 1
  for (int e = tid; e < 648; e += 256){
    int r = e / 81;
    int k = e - r*81;
    const float* cc = cC[r];
    float val;
    if (k < 36)      {               val =   cc[k/6]     * cc[9  + k%6]; }
    else if (k < 45) { int u = k-36; val = -(cc[6 + u/3] * cc[15 + u%3]); }
    else if (k < 63) { int u = k-45; val =   cc[u/3]     * cc[15 + u%3]; }
    else             { int u = k-63; val = -(cc[6 + u/6] * cc[9  + u%6]); }
    tA[r][k] = val;
  }
  __syncthreads();
#pragma unroll 1
  for (int jj = 0; jj < 3; jj++){
    int o = jj*256 + tid;
    int idxA = 0, idxB = 0; float sgn = 0.f;
    if (o < 270)      {              idxA = o/6;      idxB = o - (o/6)*6; sgn =  1.f; }
    else if (o < 378) { int t = o-270; idxA = 45 + t/3; idxB = 6 + t%3;   sgn = -1.f; }
    else if (o < 513) { int t = o-378; idxA = t/3;      idxB = 6 + t%3;   sgn =  1.f; }
    else if (o < 729) { int t = o-513; idxA = 45 + t/6; idxB = t%6;       sgn = -1.f; }
#pragma unroll
    for (int r = 0; r < 8; r++){
      float v = sgn * tA[r][idxA] * tB[r][idxB] * ivk[r];
      size_t oi = (size_t)(lrow0 + r) * 768 + o;
      fh[oi] = f2bf(v);
    }
  }
}

// ---------------------------------------------------------------------------
// Single-tower GEMM, pure bf16 1-pass: C = Ahi*Bhi.
// 256x256 block tile, BK=32, 512 threads = 8 waves, wave tile 128x64.
// 2-phase K-loop {ds_read ; prefetch ; barrier ; lgkmcnt(0) ; 16 MFMA ;
// barrier}; closing vmcnt(0) once per tile (4 loads in flight).
// MODE 0: epilogue (acc+bias)^2 -> bf16 (layer 1)
// MODE 1: epilogue (acc+bias)^2 * W3[col], block-col reduce -> partial (layer 2)
// LDS: sA[2][256][32] (32KB) + sB[2][256][32] (32KB) + rowsum (4KB)
// ---------------------------------------------------------------------------
#define GEMM_SMEM_BYTES (2*16384*2 + 4*256*4)

#define STAGE_A(BUF)  do{ u16* _a = sA + (BUF)*8192; \
    gld_lds16(gAh0, _a + wave*1024); gld_lds16(gAh1, _a + wave*1024 + 512); \
    gAh0 += 32; gAh1 += 32; }while(0)
#define STAGE_B(BUF) do{ u16* _b = sB + (BUF)*8192; \
    gld_lds16(gBh0, _b + wave*1024); gld_lds16(gBh1, _b + wave*1024 + 512); \
    gBh0 += 32; gBh1 += 32; }while(0)

#define BARRIER()  asm volatile("s_barrier" ::: "memory")
#define LGKM0()    asm volatile("s_waitcnt lgkmcnt(0)" ::: "memory")

#define CLUSTER(A, O, B) do{ \
    __builtin_amdgcn_s_setprio(1); \
    _Pragma("unroll") for (int m_ = 0; m_ < 4; m_++) \
      _Pragma("unroll") for (int n_ = 0; n_ < 4; n_++) \
        acc[(O)+m_][n_] = __builtin_amdgcn_mfma_f32_16x16x32_bf16((A)[m_], (B)[n_], acc[(O)+m_][n_], 0, 0, 0); \
    __builtin_amdgcn_s_setprio(0); \
  }while(0)

template<int MODE>
__global__ __launch_bounds__(512, 1) void gemm_k(
    const u16* __restrict__ Ahi,
    const u16* __restrict__ Bhi,
    const float* __restrict__ bias,
    u16* __restrict__ Oh,
    const float* __restrict__ W3, float* __restrict__ P, int Pstride,
    int K)
{
  extern __shared__ __align__(16) u16 smem[];
  u16* sA = smem;                                  // [2][256][32]
  u16* sB = smem + 16384;                          // [2][256][32]
  float* rowsum = (float*)(smem + 32768);          // [4][256] (MODE 1)

  // bijective XCD swizzle (guarded for tiny grids)
  const int nwg = gridDim.x;
  const int qq = nwg >> 3;
  const int wg = (nwg & 7) ? (int)blockIdx.x
                           : ((blockIdx.x & 7) * qq + (blockIdx.x >> 3));
  const int nb = wg & 3;
  const int mb = wg >> 2;

  const int tid = threadIdx.x;
  const int wave = tid >> 6, lane = tid & 63;
  const int wm = wave >> 2, wn = wave & 3;    // 2 row-halves x 4 col-quarters

  // staging addressing (rule-21 pair: inverse-swizzled global source, linear LDS)
  const int l4 = lane >> 2, ls = lane & 3;
  const int fsw  = (l4 >> 1) & 3;
  const int koff = ((ls ^ fsw) << 3);

  const u16* gAh0 = Ahi + (size_t)(mb*256 + wave*32 + l4) * K + koff;
  const u16* gAh1 = gAh0 + (size_t)16 * K;
  const u16* gBh0 = Bhi + (size_t)(nb*256 + wave*32 + l4) * K + koff;
  const u16* gBh1 = gBh0 + (size_t)16 * K;

  // fragment addressing (swizzled ds_read)
  const int r16 = lane & 15, g = lane >> 4;
  const int fr   = (r16 >> 1) & 3;
  const int slot = ((g ^ fr) << 3);

  f32x4 acc[8][4];
#pragma unroll
  for (int m = 0; m < 8; m++)
#pragma unroll
    for (int n = 0; n < 4; n++)
      acc[m][n] = (f32x4){0.f, 0.f, 0.f, 0.f};

  const int NT = K >> 5;          // 24 or 32
  STAGE_A(0); STAGE_B(0);
  asm volatile("s_waitcnt vmcnt(0)\n\ts_barrier" ::: "memory");

#pragma unroll 1
  for (int t = 0; t < NT; ++t){
    const int cur = t & 1, nxt = cur ^ 1;
    const u16* pA = sA + cur*8192;
    const u16* pB = sB + cur*8192;
    const bool pf = (t + 1 < NT);
    bf16x8 ah[8], bh[4];

    // ---- P1: read bh + ah0-3 ; prefetch next A ----
#pragma unroll
    for (int n = 0; n < 4; n++) bh[n] = *(const bf16x8*)(pB + (wn*64 + n*16 + r16)*32 + slot);
#pragma unroll
    for (int m = 0; m < 4; m++) ah[m] = *(const bf16x8*)(pA + (wm*128 + m*16 + r16)*32 + slot);
    if (pf){ STAGE_A(nxt); }
    BARRIER(); LGKM0();
    CLUSTER(ah, 0, bh);
    BARRIER();

    // ---- P2: read ah4-7 ; prefetch next B ; closing vmcnt ----
#pragma unroll
    for (int m = 0; m < 4; m++) ah[4+m] = *(const bf16x8*)(pA + (wm*128 + (4+m)*16 + r16)*32 + slot);
    if (pf){ STAGE_B(nxt); }
    BARRIER(); LGKM0();
    CLUSTER(ah+4, 4, bh);
    if (pf){
      asm volatile("s_waitcnt vmcnt(0)\n\ts_barrier" ::: "memory");
    } else {
      BARRIER();
    }
  }

  if constexpr (MODE == 0){
#pragma unroll
    for (int n = 0; n < 4; n++){
      int col = nb*256 + wn*64 + n*16 + r16;
      float bv = bias[col];
#pragma unroll
      for (int m = 0; m < 8; m++){
        int rbase = mb*256 + wm*128 + m*16 + g*4;
#pragma unroll
        for (int q = 0; q < 4; q++){
          float val = acc[m][n][q] + bv;
          val = val * val;
          size_t oi = (size_t)(rbase + q) * 1024 + col;
          Oh[oi] = f2bf(val);
        }
      }
    }
  } else {
    float w3v[4], bv[4];
#pragma unroll
    for (int n = 0; n < 4; n++){
      int col = nb*256 + wn*64 + n*16 + r16;
      w3v[n] = W3[col];
      bv[n]  = bias[col];
    }
    float rp[8][4];
#pragma unroll
    for (int m = 0; m < 8; m++)
#pragma unroll
      for (int q = 0; q < 4; q++)
        rp[m][q] = 0.f;
#pragma unroll
    for (int m = 0; m < 8; m++)
#pragma unroll
      for (int n = 0; n < 4; n++)
#pragma unroll
        for (int q = 0; q < 4; q++){
          float v = acc[m][n][q] + bv[n];
          rp[m][q] += v * v * w3v[n];
        }
#pragma unroll
    for (int m = 0; m < 8; m++)
#pragma unroll
      for (int q = 0; q < 4; q++){
        float s = rp[m][q];
        s += __shfl_xor(s, 1); s += __shfl_xor(s, 2);
        s += __shfl_xor(s, 4); s += __shfl_xor(s, 8);
        rp[m][q] = s;
      }
    if (r16 == 0){
#pragma unroll
      for (int m = 0; m < 8; m++)
#pragma unroll
        for (int q = 0; q < 4; q++)
          rowsum[wn*256 + wm*128 + m*16 + g*4 + q] = rp[m][q];
    }
    __syncthreads();
    if (tid < 256){
      float s = rowsum[tid] + rowsum[256 + tid] + rowsum[512 + tid] + rowsum[768 + tid];
      P[(size_t)nb * Pstride + mb*256 + tid] = s;
    }
  }
}

// ---------------------------------------------------------------------------
// finalize: a3 = b3 + sum_j partial[j][row]; out = clip(2log|a3a|*Wfa - ..b..)
// ---------------------------------------------------------------------------
__global__ void finalize_kernel(const float* __restrict__ Pa, const float* __restrict__ Pb,
                                int Pstride,
                                const float* __restrict__ b3a, const float* __restrict__ Wfa,
                                const float* __restrict__ b3b, const float* __restrict__ Wfb,
                                float* __restrict__ out, int row0, int Rc)
{
  int r = blockIdx.x * 256 + threadIdx.x;
  if (r >= Rc) return;
  float sa = b3a[0], sb = b3b[0];
#pragma unroll
  for (int j = 0; j < 4; j++){
    sa += Pa[(size_t)j * Pstride + r];
    sb += Pb[(size_t)j * Pstride + r];
  }
  float ta = 2.f * logf(fabsf(sa)) * Wfa[0];
  float tb = 2.f * logf(fabsf(sb)) * Wfb[0];
  float o = ta - tb;
  o = fminf(fmaxf(o, -1000000.f), 1000000.f);
  out[row0 + r] = o;
}

// ---------------------------------------------------------------------------
static inline size_t align256(size_t v){ return (v + 255) & ~(size_t)255; }

extern "C" void kernel_launch(void* const* d_in, const int* in_sizes, int n_in,
                              void* d_out, int out_size, void* d_ws, size_t ws_size,
                              hipStream_t stream)
{
  (void)n_in; (void)out_size;
  const float* x   = (const float*)d_in[0];
  const float* W1a = (const float*)d_in[1];
  const float* b1a = (const float*)d_in[2];
  const float* W2a = (const float*)d_in[3];
  const float* b2a = (const float*)d_in[4];
  const float* W3a = (const float*)d_in[5];
  const float* b3a = (const float*)d_in[6];
  const float* Wfa = (const float*)d_in[7];
  const float* W1b = (const float*)d_in[8];
  const float* b1b = (const float*)d_in[9];
  const float* W2b = (const float*)d_in[10];
  const float* b2b = (const float*)d_in[11];
  const float* W3b = (const float*)d_in[12];
  const float* b3b = (const float*)d_in[13];
  const float* Wfb = (const float*)d_in[14];
  float* out = (float*)d_out;

  const int B  = in_sizes[0] / 18;
  const int K1 = 768;
  const int K2 = 1024;

  hipFuncSetAttribute((const void*)gemm_k<0>,
                      hipFuncAttributeMaxDynamicSharedMemorySize, GEMM_SMEM_BYTES);
  hipFuncSetAttribute((const void*)gemm_k<1>,
                      hipFuncAttributeMaxDynamicSharedMemorySize, GEMM_SMEM_BYTES);

  char* base = (char*)d_ws;
  size_t off = 0;
  auto carve = [&](size_t bytes) -> char* {
    off = align256(off);
    char* p = base + off;
    off += bytes;
    return p;
  };

  u16* wt1a = (u16*)carve((size_t)1024 * K1 * 2);
  u16* wt2a = (u16*)carve((size_t)1024 * K2 * 2);
  u16* wt1b = (u16*)carve((size_t)1024 * K1 * 2);
  u16* wt2b = (u16*)carve((size_t)1024 * K2 * 2);

  size_t fixed = align256(off);
  // per-row live set: feats (1536) + one tower's h1 (2048) + partials (32)
  const long long per_row = (long long)K1*2 + 2048 + 32;
  long long avail = (long long)ws_size - (long long)fixed - 8192;
  long long rmax = avail > 0 ? avail / per_row : 0;
  int R = (int)((rmax / 256) * 256);
  if (R > B) R = B;
  if (R < 256) R = 256;

  u16* fh  = (u16*)carve((size_t)R * K1 * 2);
  u16* h1h = (u16*)carve((size_t)R * 1024 * 2);   // reused by both towers
  float* pa = (float*)carve((size_t)4 * R * 4);
  float* pb = (float*)carve((size_t)4 * R * 4);

  // all four weight transposes in one dispatch
  wconv_kernel<<<dim3(32, 32, 4), 256, 0, stream>>>(
      W1a, wt1a, K1,
      W2a, wt2a, K2,
      W1b, wt1b, K1,
      W2b, wt2b, K2);

  for (int row0 = 0; row0 < B; row0 += R){
    int Rc = B - row0; if (Rc > R) Rc = R;
    int MB = Rc / 256;
    feats_kernel<<<Rc/8, 256, 0, stream>>>(x, fh, row0);
    // tower a
    gemm_k<0><<<dim3(4*MB), 512, GEMM_SMEM_BYTES, stream>>>(
        fh, wt1a, b1a, h1h, nullptr, nullptr, 0, K1);
    gemm_k<1><<<dim3(4*MB), 512, GEMM_SMEM_BYTES, stream>>>(
        h1h, wt2a, b2a, nullptr, W3a, pa, R, K2);
    // tower b (reuses h1 buffer)
    gemm_k<0><<<dim3(4*MB), 512, GEMM_SMEM_BYTES, stream>>>(
        fh, wt1b, b1b, h1h, nullptr, nullptr, 0, K1);
    gemm_k<1><<<dim3(4*MB), 512, GEMM_SMEM_BYTES, stream>>>(
        h1h, wt2b, b2b, nullptr, W3b, pb, R, K2);
    finalize_kernel<<<(Rc + 255)/256, 256, 0, stream>>>(pa, pb, R, b3a, Wfa, b3b, Wfb,
                                                        out, row0, Rc);
  }
}